// Round 4
// baseline (363.262 us; speedup 1.0000x reference)
//
#include <hip/hip_runtime.h>
#include <hip/hip_bf16.h>
#include <stdint.h>

typedef _Float16 f16x8 __attribute__((ext_vector_type(8)));
typedef _Float16 f16x4 __attribute__((ext_vector_type(4)));
typedef uint32_t u32x2 __attribute__((ext_vector_type(2)));
typedef float floatx4 __attribute__((ext_vector_type(4)));

#define NSEQ 4096
#define DIMM 768
#define NHEADS 12
#define HD 64

__device__ __forceinline__ void gload_lds16(const void* g, void* l) {
  typedef __attribute__((address_space(1))) const uint32_t GQ;
  typedef __attribute__((address_space(3))) uint32_t LQ;
  __builtin_amdgcn_global_load_lds((GQ*)g, (LQ*)l, 16, 0, 0);
}

__device__ __forceinline__ uint16_t f16_bits(float v) {
  _Float16 h = (_Float16)v;
  return __builtin_bit_cast(uint16_t, h);
}

// v_cvt_pkrtz_f16_f32: pack two f32 -> two f16 in one instruction
__device__ __forceinline__ uint32_t pkrtz(float a, float b) {
  return __builtin_bit_cast(uint32_t, __builtin_amdgcn_cvt_pkrtz(a, b));
}

// XOR-swizzled 64-elem-row tile: 16B unit u of row r lives at physical unit
// u ^ (r&7). Spreads (stride ≡ 0 mod 32 dwords) rows across all 32 banks.
__device__ __forceinline__ int swz(int row, int e) {
  return row * 64 + ((((e >> 3) ^ (row & 7)) << 3) | (e & 7));
}

// ---------------- fp32 -> f16 convert, 8 elems/thread -----------------------
__global__ __launch_bounds__(256) void convert_f32_f16(
    const float4* __restrict__ src, f16x8* __restrict__ dst, int n8) {
  const int i = blockIdx.x * 256 + threadIdx.x;
  if (i >= n8) return;
  const float4 a = src[2 * i], b = src[2 * i + 1];
  f16x8 o;
  o[0] = (_Float16)a.x; o[1] = (_Float16)a.y; o[2] = (_Float16)a.z; o[3] = (_Float16)a.w;
  o[4] = (_Float16)b.x; o[5] = (_Float16)b.y; o[6] = (_Float16)b.z; o[7] = (_Float16)b.w;
  dst[i] = o;
}

// ---------------- fp32 transpose+convert: dst[c][r] = f16(src[r][c]) --------
__global__ __launch_bounds__(256) void transpose_f32_f16(
    const float* __restrict__ src, uint16_t* __restrict__ dst, int R, int C) {
  __shared__ uint16_t tile[32][33];
  const int c0 = blockIdx.x * 32, r0 = blockIdx.y * 32;
  const int tx = threadIdx.x, ty = threadIdx.y;  // 32 x 8
#pragma unroll
  for (int i = 0; i < 32; i += 8)
    tile[ty + i][tx] = f16_bits(src[(size_t)(r0 + ty + i) * C + (c0 + tx)]);
  __syncthreads();
#pragma unroll
  for (int i = 0; i < 32; i += 8)
    dst[(size_t)(c0 + ty + i) * R + (r0 + tx)] = tile[tx][ty + i];
}

// ---------------- batched 16-bit transpose: dst[z][c][r] = src[z][r][c] -----
__global__ __launch_bounds__(256) void transpose_b16(
    const uint16_t* __restrict__ src, uint16_t* __restrict__ dst, int R, int C) {
  __shared__ uint16_t tile[32][33];
  const size_t plane = (size_t)blockIdx.z * (size_t)R * (size_t)C;
  const int c0 = blockIdx.x * 32, r0 = blockIdx.y * 32;
  const int tx = threadIdx.x, ty = threadIdx.y;
#pragma unroll
  for (int i = 0; i < 32; i += 8)
    tile[ty + i][tx] = src[plane + (size_t)(r0 + ty + i) * C + (c0 + tx)];
  __syncthreads();
#pragma unroll
  for (int i = 0; i < 32; i += 8)
    dst[plane + (size_t)(c0 + ty + i) * R + (r0 + tx)] = tile[tx][ty + i];
}

// ---------------- GEMM: C[m][n] = sum_k A[m][k] * Bt[n][k] + bias[n]
// 3-buffer counted-vmcnt pipeline (T4): STAGE(t+2) issued each iter, DMA
// stays in flight across barriers; vmcnt(4) drains only tile t's loads.
// mode 0: store FP32 to o0 row-major [M][768]
// mode 1: QKV scatter into o0/o1/o2 = Q/K/V [B,H,N,64] f16; Q pre-scaled
__global__ __launch_bounds__(256) void gemm_bt(
    const _Float16* __restrict__ A, const _Float16* __restrict__ Bt,
    const float* __restrict__ bias, int K, int mode,
    void* __restrict__ o0, _Float16* __restrict__ o1, _Float16* __restrict__ o2) {
  __shared__ __attribute__((aligned(16))) _Float16 As[3][128 * 32];
  __shared__ __attribute__((aligned(16))) _Float16 Bs[3][128 * 32];
  __shared__ float bias_s[128];
  const int tid = threadIdx.x;
  const int wv = tid >> 6;
  const int lane = tid & 63;
  const int quad = lane >> 4, l16 = lane & 15;
  const int wm = (wv >> 1) * 64, wn = (wv & 1) * 64;
  const int m0 = blockIdx.y * 128, n0 = blockIdx.x * 128;

  if (tid < 128) bias_s[tid] = bias[n0 + tid];

  floatx4 acc[4][4];
#pragma unroll
  for (int i = 0; i < 4; ++i)
#pragma unroll
    for (int j = 0; j < 4; ++j) acc[i][j] = (floatx4){0.f, 0.f, 0.f, 0.f};

  // DMA mapping: wave wv stages A/B tile rows [wv*32, wv*32+32).
  const int gr = lane >> 2, gc = (lane & 3) * 8;
  const _Float16* Ag = A + (size_t)(m0 + wv * 32 + gr) * K + gc;
  const _Float16* Bg = Bt + (size_t)(n0 + wv * 32 + gr) * K + gc;
  const size_t K16 = (size_t)16 * K;

  auto STAGE = [&](int buf, int kt) {
    _Float16* As0 = &As[buf][wv * 1024];
    _Float16* Bs0 = &Bs[buf][wv * 1024];
    gload_lds16(Ag + kt, As0);
    gload_lds16(Ag + kt + K16, As0 + 512);
    gload_lds16(Bg + kt, Bs0);
    gload_lds16(Bg + kt + K16, Bs0 + 512);
  };
  auto COMPUTE = [&](int buf) {
    f16x8 af[4], bfr[4];
#pragma unroll
    for (int i = 0; i < 4; ++i)
      af[i] = *(const f16x8*)&As[buf][(wm + i * 16 + l16) * 32 + quad * 8];
#pragma unroll
    for (int j = 0; j < 4; ++j)
      bfr[j] = *(const f16x8*)&Bs[buf][(wn + j * 16 + l16) * 32 + quad * 8];
    __builtin_amdgcn_s_setprio(1);
#pragma unroll
    for (int i = 0; i < 4; ++i)
#pragma unroll
      for (int j = 0; j < 4; ++j)
        acc[i][j] = __builtin_amdgcn_mfma_f32_16x16x32_f16(af[i], bfr[j], acc[i][j], 0, 0, 0);
    __builtin_amdgcn_s_setprio(0);
  };

  STAGE(0, 0);
  STAGE(1, 32);
  const int nt = K >> 5;
  int b0 = 0, b1 = 1, b2 = 2;
#pragma unroll 1
  for (int t = 0; t < nt - 2; ++t) {
    // tile t landed (its 4 loads are the oldest; 4 newer stay in flight)
    asm volatile("s_waitcnt vmcnt(4)" ::: "memory");
    __builtin_amdgcn_s_barrier();
    STAGE(b2, (t + 2) * 32);
    COMPUTE(b0);
    const int tmp = b0; b0 = b1; b1 = b2; b2 = tmp;
  }
  asm volatile("s_waitcnt vmcnt(4)" ::: "memory");
  __builtin_amdgcn_s_barrier();
  COMPUTE(b0);
  b0 = b1;
  asm volatile("s_waitcnt vmcnt(0)" ::: "memory");
  __builtin_amdgcn_s_barrier();
  COMPUTE(b0);

  if (mode == 0) {
    float* of = (float*)o0;
#pragma unroll
    for (int i = 0; i < 4; ++i)
#pragma unroll
      for (int j = 0; j < 4; ++j) {
        const int col = n0 + wn + j * 16 + l16;
        const float b = bias_s[wn + j * 16 + l16];
        const int mrow = m0 + wm + i * 16 + quad * 4;
#pragma unroll
        for (int r = 0; r < 4; ++r)
          of[(size_t)(mrow + r) * DIMM + col] = acc[i][j][r] + b;
      }
  } else {
    const int sec = n0 / DIMM;  // 0=Q 1=K 2=V
    _Float16* dst = (sec == 0) ? (_Float16*)o0 : (sec == 1) ? o1 : o2;
    const float sc = (sec == 0) ? 0.18033688011112042f : 1.0f;  // 1/8 * log2(e)
#pragma unroll
    for (int i = 0; i < 4; ++i)
#pragma unroll
      for (int j = 0; j < 4; ++j) {
        const int n = n0 + wn + j * 16 + l16;
        const int c = n - sec * DIMM;
        const int h = c >> 6, d = c & 63;
        const float b = bias_s[wn + j * 16 + l16];
        const int mrow = m0 + wm + i * 16 + quad * 4;
#pragma unroll
        for (int r = 0; r < 4; ++r) {
          const int m = mrow + r;
          const int bb = m >> 12, nr = m & 4095;
          dst[(((size_t)(bb * NHEADS + h)) * NSEQ + nr) * HD + d] =
              (_Float16)((acc[i][j][r] + b) * sc);
        }
      }
  }
}

// ---------------- flash attention v6: LDS-BW diet. K stays LDS (DMA +
// swizzle); V goes DIRECT global->reg (L1/L2-resident per XCD swizzle),
// removing LDVR LDS reads + V-DMA + VTs buffers (LDS 48->32KB, -36% LDS
// traffic). Row-sum l computed via MFMA against ones (kills VALU adds +
// epilogue shuffles). Pipelined: region t does QK^T(t)+PV(t-1). ------------
__global__ __launch_bounds__(256, 3) void attn(
    const _Float16* __restrict__ Qg, const _Float16* __restrict__ Kg,
    const _Float16* __restrict__ VTg, _Float16* __restrict__ ctx) {
  __shared__ __attribute__((aligned(16))) _Float16 Pt[128 * 64];  // Q stage / P
  __shared__ __attribute__((aligned(16))) _Float16 Ks[2][64 * 64];
  const int tid = threadIdx.x;
  const int wv = tid >> 6, lane = tid & 63;
  const int quad = lane >> 4, l16 = lane & 15;
  // XCD swizzle: 768 blocks; id%8 = XCD -> each XCD owns 3 bh (K/V L2-resident)
  const int bi = blockIdx.x;
  const int xcd = bi & 7, j = bi >> 3;
  const int bh = xcd * 3 + (j >> 5);
  const int q0 = (j & 31) * 128;
  const int bb = bh / NHEADS, h = bh - bb * NHEADS;
  const _Float16* Qp = Qg + (size_t)bh * NSEQ * HD;
  const _Float16* Kp = Kg + (size_t)bh * NSEQ * HD;
  const _Float16* VTp = VTg + (size_t)bh * HD * NSEQ;

  const int krow = tid >> 3;
  // DMA lane->global-unit permute implements the XOR swizzle
  const int kcol = (((tid & 7) ^ ((tid >> 3) & 7)) * 8);
  const int l7 = l16 & 7;

  // preamble: DMA Q tile [128][64] into Pt area + K tile 0/1 into Ks
#pragma unroll
  for (int i = 0; i < 4; ++i)
    gload_lds16(Qp + (size_t)(q0 + i * 32 + krow) * HD + kcol, &Pt[(i * 256 + wv * 64) * 8]);
#pragma unroll
  for (int i = 0; i < 2; ++i)
    gload_lds16(Kp + (size_t)(i * 32 + krow) * HD + kcol, &Ks[0][(i * 256 + wv * 64) * 8]);
  __syncthreads();  // drains DMA: Q + K0 visible

  f16x8 aq[2][2];
#pragma unroll
  for (int it = 0; it < 2; ++it)
#pragma unroll
    for (int ks = 0; ks < 2; ++ks)
      aq[it][ks] = *(const f16x8*)&Pt[swz(wv * 32 + it * 16 + l16, ks * 32 + quad * 8)];

  // K(1) prefetch -> Ks[1] (drained at region 1's barrier)
#pragma unroll
  for (int i = 0; i < 2; ++i)
    gload_lds16(Kp + (size_t)(64 + i * 32 + krow) * HD + kcol, &Ks[1][(i * 256 + wv * 64) * 8]);

  f16x8 ones;
#pragma unroll
  for (int e = 0; e < 8; ++e) ones[e] = (_Float16)1.0f;

  floatx4 o[2][4];
  floatx4 lacc[2];
#pragma unroll
  for (int it = 0; it < 2; ++it) {
    lacc[it] = (floatx4){0.f, 0.f, 0.f, 0.f};
#pragma unroll
    for (int jn = 0; jn < 4; ++jn) o[it][jn] = (floatx4){0.f, 0.f, 0.f, 0.f};
  }

  const int prow = wv * 32 + l16;
  f16x8 vr[2][4];  // V(t) fragments, loaded direct from global (L1/L2)

  auto VLOAD = [&](int vn) {
    const _Float16* vp = VTp + vn;
#pragma unroll
    for (int kk = 0; kk < 2; ++kk)
#pragma unroll
      for (int jn = 0; jn < 4; ++jn)
        vr[kk][jn] = *(const f16x8*)(vp + (size_t)(jn * 16 + l16) * NSEQ + kk * 32 + quad * 8);
  };
  // S^T = K . Q^T  (exp2-domain: Q pre-scaled by 0.125*log2e)
  auto QKT = [&](const _Float16* bK, floatx4 (&s)[2][4]) {
#pragma unroll
    for (int ks = 0; ks < 2; ++ks) {
#pragma unroll
      for (int im = 0; im < 4; ++im) {
        const f16x8 bk = *(const f16x8*)&bK[swz(im * 16 + l16, ks * 32 + quad * 8)];
        s[0][im] = __builtin_amdgcn_mfma_f32_16x16x32_f16(bk, aq[0][ks], s[0][im], 0, 0, 0);
        s[1][im] = __builtin_amdgcn_mfma_f32_16x16x32_f16(bk, aq[1][ks], s[1][im], 0, 0, 0);
      }
    }
  };
  // p = exp2(s); pack via native pkrtz; b64 P stores (l handled by MFMA)
  auto SMAX = [&](floatx4 (&s)[2][4]) {
#pragma unroll
    for (int it = 0; it < 2; ++it) {
      const int row = prow + it * 16;
#pragma unroll
      for (int im = 0; im < 4; ++im) {
        float p0 = __builtin_amdgcn_exp2f(s[it][im][0]);
        float p1 = __builtin_amdgcn_exp2f(s[it][im][1]);
        float p2 = __builtin_amdgcn_exp2f(s[it][im][2]);
        float p3 = __builtin_amdgcn_exp2f(s[it][im][3]);
        const u32x2 packed = {pkrtz(p0, p1), pkrtz(p2, p3)};
        *(f16x4*)&Pt[row * 64 + (((im * 2 + (quad >> 1)) ^ l7) << 3) + (quad & 1) * 4] =
            __builtin_bit_cast(f16x4, packed);
      }
    }
  };
  auto LDAP = [&](f16x8 (&ap)[2][2]) {
#pragma unroll
    for (int kk = 0; kk < 2; ++kk) {
      ap[kk][0] = *(const f16x8*)&Pt[swz(prow, kk * 32 + quad * 8)];
      ap[kk][1] = *(const f16x8*)&Pt[swz(prow + 16, kk * 32 + quad * 8)];
    }
  };
  auto PV = [&](const f16x8 (&ap)[2][2]) {
#pragma unroll
    for (int kk = 0; kk < 2; ++kk) {
      lacc[0] = __builtin_amdgcn_mfma_f32_16x16x32_f16(ap[kk][0], ones, lacc[0], 0, 0, 0);
      lacc[1] = __builtin_amdgcn_mfma_f32_16x16x32_f16(ap[kk][1], ones, lacc[1], 0, 0, 0);
#pragma unroll
      for (int jn = 0; jn < 4; ++jn) {
        o[0][jn] = __builtin_amdgcn_mfma_f32_16x16x32_f16(ap[kk][0], vr[kk][jn], o[0][jn], 0, 0, 0);
        o[1][jn] = __builtin_amdgcn_mfma_f32_16x16x32_f16(ap[kk][1], vr[kk][jn], o[1][jn], 0, 0, 0);
      }
    }
  };

  // V(0) direct loads (consumed by PV in region 1; latency covered)
  VLOAD(0);

  // region 0: QK^T(0), softmax(0) -> P(0)
  {
    floatx4 s[2][4];
#pragma unroll
    for (int it = 0; it < 2; ++it)
#pragma unroll
      for (int im = 0; im < 4; ++im) s[it][im] = (floatx4){0.f, 0.f, 0.f, 0.f};
    __builtin_amdgcn_s_setprio(1);
    QKT(Ks[0], s);
    __builtin_amdgcn_s_setprio(0);
    SMAX(s);
  }

  // region t: barrier (K(t)+V(t-1) loads drained); K-DMA(t+1); cluster
  // QK^T(t)+PV(t-1); VLOAD(t) after PV (WAR on vr, in-order issue safe);
  // softmax(t) tail.
  auto REGION = [&](const _Float16* bK, _Float16* wK, int t, bool dodma) {
    __syncthreads();
    if (dodma) {
      const int kvn = ((t + 1) & 63) * 64;
#pragma unroll
      for (int i = 0; i < 2; ++i)
        gload_lds16(Kp + (size_t)(kvn + i * 32 + krow) * HD + kcol, &wK[(i * 256 + wv * 64) * 8]);
    }
    f16x8 ap[2][2];
    LDAP(ap);  // P(t-1), wave-private rows
    floatx4 s[2][4];
#pragma unroll
    for (int it = 0; it < 2; ++it)
#pragma unroll
      for (int im = 0; im < 4; ++im) s[it][im] = (floatx4){0.f, 0.f, 0.f, 0.f};
    __builtin_amdgcn_s_setprio(1);
    QKT(bK, s);
    PV(ap);  // consumes vr = V(t-1)
    __builtin_amdgcn_s_setprio(0);
    VLOAD(t * 64);  // vr = V(t); waited by next region's PV
    SMAX(s);        // stores P(t)
  };

#pragma unroll 1
  for (int p = 0; p < 31; ++p) {
    const int t = 2 * p + 1;
    REGION(Ks[1], Ks[0], t, true);
    REGION(Ks[0], Ks[1], t + 1, true);
  }
  REGION(Ks[1], Ks[0], 63, false);
  // final PV(63): P in own rows, V in vr
  {
    f16x8 ap[2][2];
    LDAP(ap);
    PV(ap);
  }

  // epilogue: l[q] sits in lacc[it][r] for q-row quad*4+r -- no shuffles
#pragma unroll
  for (int it = 0; it < 2; ++it)
#pragma unroll
    for (int r = 0; r < 4; ++r) {
      const int q = q0 + wv * 32 + it * 16 + quad * 4 + r;
      const float inv = 1.0f / lacc[it][r];
      _Float16* dst = ctx + (size_t)(bb * NSEQ + q) * DIMM + h * HD;
#pragma unroll
      for (int jn = 0; jn < 4; ++jn)
        dst[jn * 16 + l16] = (_Float16)(o[it][jn][r] * inv);
    }
}

extern "C" void kernel_launch(void* const* d_in, const int* in_sizes, int n_in,
                              void* d_out, int out_size, void* d_ws, size_t ws_size,
                              hipStream_t stream) {
  char* ws = (char*)d_ws;
  _Float16* xc = (_Float16*)ws;      ws += (size_t)8192 * 768 * 2;
  _Float16* wqkvT = (_Float16*)ws;   ws += (size_t)2304 * 768 * 2;
  _Float16* wprojT = (_Float16*)ws;  ws += (size_t)768 * 768 * 2;
  const size_t qkv_elems = (size_t)2 * NHEADS * NSEQ * HD;
  _Float16* Qb = (_Float16*)ws;      ws += qkv_elems * 2;
  _Float16* Kb = (_Float16*)ws;      ws += qkv_elems * 2;
  _Float16* Vb = (_Float16*)ws;      ws += qkv_elems * 2;
  _Float16* VTb = (_Float16*)ws;     ws += qkv_elems * 2;
  _Float16* ctx = xc;  // x dead after QKV GEMM; reuse as attention output

  const dim3 tb(32, 8, 1);
  const dim3 b256(256, 1, 1);
  hipLaunchKernelGGL(convert_f32_f16, dim3(3072, 1, 1), b256, 0, stream,
                     (const float4*)d_in[0], (f16x8*)xc, 8192 * 768 / 8);
  hipLaunchKernelGGL(transpose_f32_f16, dim3(72, 24, 1), tb, 0, stream,
                     (const float*)d_in[1], (uint16_t*)wqkvT, 768, 2304);
  hipLaunchKernelGGL(transpose_f32_f16, dim3(24, 24, 1), tb, 0, stream,
                     (const float*)d_in[3], (uint16_t*)wprojT, 768, 768);
  hipLaunchKernelGGL(gemm_bt, dim3(18, 64, 1), b256, 0, stream,
                     xc, wqkvT, (const float*)d_in[2], 768, 1, (void*)Qb, Kb, Vb);
  hipLaunchKernelGGL(transpose_b16, dim3(2, 128, 24), tb, 0, stream,
                     (const uint16_t*)Vb, (uint16_t*)VTb, 4096, 64);
  hipLaunchKernelGGL(attn, dim3(768, 1, 1), b256, 0, stream, Qb, Kb, VTb, ctx);
  hipLaunchKernelGGL(gemm_bt, dim3(6, 64, 1), b256, 0, stream,
                     ctx, wprojT, (const float*)d_in[4], 768, 0, d_out,
                     (_Float16*)nullptr, (_Float16*)nullptr);
}

// Round 5
// 286.217 us; speedup vs baseline: 1.2692x; 1.2692x over previous
//
#include <hip/hip_runtime.h>
#include <hip/hip_bf16.h>
#include <stdint.h>

typedef _Float16 f16x8 __attribute__((ext_vector_type(8)));
typedef _Float16 f16x4 __attribute__((ext_vector_type(4)));
typedef uint32_t u32x2 __attribute__((ext_vector_type(2)));
typedef float floatx4 __attribute__((ext_vector_type(4)));

#define NSEQ 4096
#define DIMM 768
#define NHEADS 12
#define HD 64

__device__ __forceinline__ void gload_lds16(const void* g, void* l) {
  typedef __attribute__((address_space(1))) const uint32_t GQ;
  typedef __attribute__((address_space(3))) uint32_t LQ;
  __builtin_amdgcn_global_load_lds((GQ*)g, (LQ*)l, 16, 0, 0);
}

__device__ __forceinline__ uint16_t f16_bits(float v) {
  _Float16 h = (_Float16)v;
  return __builtin_bit_cast(uint16_t, h);
}

// v_cvt_pkrtz_f16_f32: pack two f32 -> two f16 in one instruction
__device__ __forceinline__ uint32_t pkrtz(float a, float b) {
  return __builtin_bit_cast(uint32_t, __builtin_amdgcn_cvt_pkrtz(a, b));
}

// XOR-swizzled 64-elem-row tile: 16B unit u of row r lives at physical unit
// u ^ (r&7). Spreads (stride ≡ 0 mod 32 dwords) rows across all 32 banks.
__device__ __forceinline__ int swz(int row, int e) {
  return row * 64 + ((((e >> 3) ^ (row & 7)) << 3) | (e & 7));
}

// ---------------- fp32 -> f16 convert, 8 elems/thread -----------------------
__global__ __launch_bounds__(256) void convert_f32_f16(
    const float4* __restrict__ src, f16x8* __restrict__ dst, int n8) {
  const int i = blockIdx.x * 256 + threadIdx.x;
  if (i >= n8) return;
  const float4 a = src[2 * i], b = src[2 * i + 1];
  f16x8 o;
  o[0] = (_Float16)a.x; o[1] = (_Float16)a.y; o[2] = (_Float16)a.z; o[3] = (_Float16)a.w;
  o[4] = (_Float16)b.x; o[5] = (_Float16)b.y; o[6] = (_Float16)b.z; o[7] = (_Float16)b.w;
  dst[i] = o;
}

// ---------------- fp32 transpose+convert: dst[c][r] = f16(src[r][c]) --------
__global__ __launch_bounds__(256) void transpose_f32_f16(
    const float* __restrict__ src, uint16_t* __restrict__ dst, int R, int C) {
  __shared__ uint16_t tile[32][33];
  const int c0 = blockIdx.x * 32, r0 = blockIdx.y * 32;
  const int tx = threadIdx.x, ty = threadIdx.y;  // 32 x 8
#pragma unroll
  for (int i = 0; i < 32; i += 8)
    tile[ty + i][tx] = f16_bits(src[(size_t)(r0 + ty + i) * C + (c0 + tx)]);
  __syncthreads();
#pragma unroll
  for (int i = 0; i < 32; i += 8)
    dst[(size_t)(c0 + ty + i) * R + (r0 + tx)] = tile[tx][ty + i];
}

// ---------------- batched 16-bit transpose: dst[z][c][r] = src[z][r][c] -----
__global__ __launch_bounds__(256) void transpose_b16(
    const uint16_t* __restrict__ src, uint16_t* __restrict__ dst, int R, int C) {
  __shared__ uint16_t tile[32][33];
  const size_t plane = (size_t)blockIdx.z * (size_t)R * (size_t)C;
  const int c0 = blockIdx.x * 32, r0 = blockIdx.y * 32;
  const int tx = threadIdx.x, ty = threadIdx.y;
#pragma unroll
  for (int i = 0; i < 32; i += 8)
    tile[ty + i][tx] = src[plane + (size_t)(r0 + ty + i) * C + (c0 + tx)];
  __syncthreads();
#pragma unroll
  for (int i = 0; i < 32; i += 8)
    dst[plane + (size_t)(c0 + ty + i) * R + (r0 + tx)] = tile[tx][ty + i];
}

// ---------------- GEMM: C[m][n] = sum_k A[m][k] * Bt[n][k] + bias[n]
// 3-buffer counted-vmcnt pipeline (T4): STAGE(t+2) issued each iter, DMA
// stays in flight across barriers; vmcnt(4) drains only tile t's loads.
// mode 0: store FP32 to o0 row-major [M][768]
// mode 1: QKV scatter into o0/o1/o2 = Q/K/V [B,H,N,64] f16; Q pre-scaled
__global__ __launch_bounds__(256) void gemm_bt(
    const _Float16* __restrict__ A, const _Float16* __restrict__ Bt,
    const float* __restrict__ bias, int K, int mode,
    void* __restrict__ o0, _Float16* __restrict__ o1, _Float16* __restrict__ o2) {
  __shared__ __attribute__((aligned(16))) _Float16 As[3][128 * 32];
  __shared__ __attribute__((aligned(16))) _Float16 Bs[3][128 * 32];
  __shared__ float bias_s[128];
  const int tid = threadIdx.x;
  const int wv = tid >> 6;
  const int lane = tid & 63;
  const int quad = lane >> 4, l16 = lane & 15;
  const int wm = (wv >> 1) * 64, wn = (wv & 1) * 64;
  const int m0 = blockIdx.y * 128, n0 = blockIdx.x * 128;

  if (tid < 128) bias_s[tid] = bias[n0 + tid];

  floatx4 acc[4][4];
#pragma unroll
  for (int i = 0; i < 4; ++i)
#pragma unroll
    for (int j = 0; j < 4; ++j) acc[i][j] = (floatx4){0.f, 0.f, 0.f, 0.f};

  // DMA mapping: wave wv stages A/B tile rows [wv*32, wv*32+32).
  const int gr = lane >> 2, gc = (lane & 3) * 8;
  const _Float16* Ag = A + (size_t)(m0 + wv * 32 + gr) * K + gc;
  const _Float16* Bg = Bt + (size_t)(n0 + wv * 32 + gr) * K + gc;
  const size_t K16 = (size_t)16 * K;

  auto STAGE = [&](int buf, int kt) {
    _Float16* As0 = &As[buf][wv * 1024];
    _Float16* Bs0 = &Bs[buf][wv * 1024];
    gload_lds16(Ag + kt, As0);
    gload_lds16(Ag + kt + K16, As0 + 512);
    gload_lds16(Bg + kt, Bs0);
    gload_lds16(Bg + kt + K16, Bs0 + 512);
  };
  auto COMPUTE = [&](int buf) {
    f16x8 af[4], bfr[4];
#pragma unroll
    for (int i = 0; i < 4; ++i)
      af[i] = *(const f16x8*)&As[buf][(wm + i * 16 + l16) * 32 + quad * 8];
#pragma unroll
    for (int j = 0; j < 4; ++j)
      bfr[j] = *(const f16x8*)&Bs[buf][(wn + j * 16 + l16) * 32 + quad * 8];
    __builtin_amdgcn_s_setprio(1);
#pragma unroll
    for (int i = 0; i < 4; ++i)
#pragma unroll
      for (int j = 0; j < 4; ++j)
        acc[i][j] = __builtin_amdgcn_mfma_f32_16x16x32_f16(af[i], bfr[j], acc[i][j], 0, 0, 0);
    __builtin_amdgcn_s_setprio(0);
  };

  STAGE(0, 0);
  STAGE(1, 32);
  const int nt = K >> 5;
  int b0 = 0, b1 = 1, b2 = 2;
#pragma unroll 1
  for (int t = 0; t < nt - 2; ++t) {
    // tile t landed (its 4 loads are the oldest; 4 newer stay in flight)
    asm volatile("s_waitcnt vmcnt(4)" ::: "memory");
    __builtin_amdgcn_s_barrier();
    STAGE(b2, (t + 2) * 32);
    COMPUTE(b0);
    const int tmp = b0; b0 = b1; b1 = b2; b2 = tmp;
  }
  asm volatile("s_waitcnt vmcnt(4)" ::: "memory");
  __builtin_amdgcn_s_barrier();
  COMPUTE(b0);
  b0 = b1;
  asm volatile("s_waitcnt vmcnt(0)" ::: "memory");
  __builtin_amdgcn_s_barrier();
  COMPUTE(b0);

  if (mode == 0) {
    float* of = (float*)o0;
#pragma unroll
    for (int i = 0; i < 4; ++i)
#pragma unroll
      for (int j = 0; j < 4; ++j) {
        const int col = n0 + wn + j * 16 + l16;
        const float b = bias_s[wn + j * 16 + l16];
        const int mrow = m0 + wm + i * 16 + quad * 4;
#pragma unroll
        for (int r = 0; r < 4; ++r)
          of[(size_t)(mrow + r) * DIMM + col] = acc[i][j][r] + b;
      }
  } else {
    const int sec = n0 / DIMM;  // 0=Q 1=K 2=V
    _Float16* dst = (sec == 0) ? (_Float16*)o0 : (sec == 1) ? o1 : o2;
    const float sc = (sec == 0) ? 0.18033688011112042f : 1.0f;  // 1/8 * log2(e)
#pragma unroll
    for (int i = 0; i < 4; ++i)
#pragma unroll
      for (int j = 0; j < 4; ++j) {
        const int n = n0 + wn + j * 16 + l16;
        const int c = n - sec * DIMM;
        const int h = c >> 6, d = c & 63;
        const float b = bias_s[wn + j * 16 + l16];
        const int mrow = m0 + wm + i * 16 + quad * 4;
#pragma unroll
        for (int r = 0; r < 4; ++r) {
          const int m = mrow + r;
          const int bb = m >> 12, nr = m & 4095;
          dst[(((size_t)(bb * NHEADS + h)) * NSEQ + nr) * HD + d] =
              (_Float16)((acc[i][j][r] + b) * sc);
        }
      }
  }
}

// ---------------- flash attention v5 (reverted from v6 regression): f16,
// S^T form, no-max exp2 softmax, pkrtz P-pack, XOR-swizzled LDS, setprio
// MFMA clusters, software-pipelined regions: region t computes QK^T(t) +
// PV(t-1) back-to-back; V(t) carried in registers across the barrier. ------
__global__ __launch_bounds__(256, 3) void attn(
    const _Float16* __restrict__ Qg, const _Float16* __restrict__ Kg,
    const _Float16* __restrict__ VTg, _Float16* __restrict__ ctx) {
  __shared__ __attribute__((aligned(16))) _Float16 Pt[128 * 64];  // Q stage / P^T
  __shared__ __attribute__((aligned(16))) _Float16 Ks[2][64 * 64];
  __shared__ __attribute__((aligned(16))) _Float16 VTs[2][64 * 64];
  const int tid = threadIdx.x;
  const int wv = tid >> 6, lane = tid & 63;
  const int quad = lane >> 4, l16 = lane & 15;
  // XCD swizzle: 768 blocks; id%8 = XCD -> each XCD owns 3 bh (K/V L2-resident)
  const int bi = blockIdx.x;
  const int xcd = bi & 7, j = bi >> 3;
  const int bh = xcd * 3 + (j >> 5);
  const int q0 = (j & 31) * 128;
  const int bb = bh / NHEADS, h = bh - bb * NHEADS;
  const _Float16* Qp = Qg + (size_t)bh * NSEQ * HD;
  const _Float16* Kp = Kg + (size_t)bh * NSEQ * HD;
  const _Float16* VTp = VTg + (size_t)bh * HD * NSEQ;

  const int krow = tid >> 3;
  // DMA lane->global-unit permute implements the XOR swizzle
  const int kcol = (((tid & 7) ^ ((tid >> 3) & 7)) * 8);
  const int l7 = l16 & 7;

  // preamble: DMA Q tile [128][64] into Pt area + KV tile 0 into buf0
#pragma unroll
  for (int i = 0; i < 4; ++i)
    gload_lds16(Qp + (size_t)(q0 + i * 32 + krow) * HD + kcol, &Pt[(i * 256 + wv * 64) * 8]);
#pragma unroll
  for (int i = 0; i < 2; ++i) {
    gload_lds16(Kp + (size_t)(i * 32 + krow) * HD + kcol, &Ks[0][(i * 256 + wv * 64) * 8]);
    gload_lds16(VTp + (size_t)(i * 32 + krow) * NSEQ + kcol, &VTs[0][(i * 256 + wv * 64) * 8]);
  }
  __syncthreads();  // drains DMA: Q + buf0 visible

  f16x8 aq[2][2];
#pragma unroll
  for (int it = 0; it < 2; ++it)
#pragma unroll
    for (int ks = 0; ks < 2; ++ks)
      aq[it][ks] = *(const f16x8*)&Pt[swz(wv * 32 + it * 16 + l16, ks * 32 + quad * 8)];

  // issue DMA tile1 -> buf1 (drained at the first loop barrier)
#pragma unroll
  for (int i = 0; i < 2; ++i) {
    gload_lds16(Kp + (size_t)(64 + i * 32 + krow) * HD + kcol, &Ks[1][(i * 256 + wv * 64) * 8]);
    gload_lds16(VTp + (size_t)(i * 32 + krow) * NSEQ + 64 + kcol, &VTs[1][(i * 256 + wv * 64) * 8]);
  }

  floatx4 o[2][4];
  float lp[2] = {0.f, 0.f};
#pragma unroll
  for (int it = 0; it < 2; ++it)
#pragma unroll
    for (int jn = 0; jn < 4; ++jn) o[it][jn] = (floatx4){0.f, 0.f, 0.f, 0.f};

  const int prow = wv * 32 + l16;
  f16x8 vr[2][4];  // V(t) fragments carried across the barrier

  // S^T = K . Q^T  (exp2-domain: Q pre-scaled by 0.125*log2e)
  auto QKT = [&](const _Float16* bK, floatx4 (&s)[2][4]) {
#pragma unroll
    for (int ks = 0; ks < 2; ++ks) {
#pragma unroll
      for (int im = 0; im < 4; ++im) {
        const f16x8 bk = *(const f16x8*)&bK[swz(im * 16 + l16, ks * 32 + quad * 8)];
        s[0][im] = __builtin_amdgcn_mfma_f32_16x16x32_f16(bk, aq[0][ks], s[0][im], 0, 0, 0);
        s[1][im] = __builtin_amdgcn_mfma_f32_16x16x32_f16(bk, aq[1][ks], s[1][im], 0, 0, 0);
      }
    }
  };
  auto LDVR = [&](const _Float16* bV) {
#pragma unroll
    for (int kk = 0; kk < 2; ++kk)
#pragma unroll
      for (int jn = 0; jn < 4; ++jn)
        vr[kk][jn] = *(const f16x8*)&bV[swz(jn * 16 + l16, kk * 32 + quad * 8)];
  };
  // p = exp2(s); per-lane partial l; pack via native pkrtz; b64 P^T stores
  auto SMAX = [&](floatx4 (&s)[2][4]) {
#pragma unroll
    for (int it = 0; it < 2; ++it) {
      const int row = prow + it * 16;
#pragma unroll
      for (int im = 0; im < 4; ++im) {
        float p0 = __builtin_amdgcn_exp2f(s[it][im][0]);
        float p1 = __builtin_amdgcn_exp2f(s[it][im][1]);
        float p2 = __builtin_amdgcn_exp2f(s[it][im][2]);
        float p3 = __builtin_amdgcn_exp2f(s[it][im][3]);
        lp[it] += (p0 + p1) + (p2 + p3);
        const u32x2 packed = {pkrtz(p0, p1), pkrtz(p2, p3)};
        *(f16x4*)&Pt[row * 64 + (((im * 2 + (quad >> 1)) ^ l7) << 3) + (quad & 1) * 4] =
            __builtin_bit_cast(f16x4, packed);
      }
    }
  };
  auto LDAP = [&](f16x8 (&ap)[2][2]) {
#pragma unroll
    for (int kk = 0; kk < 2; ++kk) {
      ap[kk][0] = *(const f16x8*)&Pt[swz(prow, kk * 32 + quad * 8)];
      ap[kk][1] = *(const f16x8*)&Pt[swz(prow + 16, kk * 32 + quad * 8)];
    }
  };
  auto PV = [&](const f16x8 (&ap)[2][2]) {
#pragma unroll
    for (int kk = 0; kk < 2; ++kk) {
#pragma unroll
      for (int jn = 0; jn < 4; ++jn) {
        o[0][jn] = __builtin_amdgcn_mfma_f32_16x16x32_f16(ap[kk][0], vr[kk][jn], o[0][jn], 0, 0, 0);
        o[1][jn] = __builtin_amdgcn_mfma_f32_16x16x32_f16(ap[kk][1], vr[kk][jn], o[1][jn], 0, 0, 0);
      }
    }
  };

  // region 0 (no PV): QK^T(0), stash V(0) in regs, softmax(0) -> P(0)
  {
    floatx4 s[2][4];
#pragma unroll
    for (int it = 0; it < 2; ++it)
#pragma unroll
      for (int im = 0; im < 4; ++im) s[it][im] = (floatx4){0.f, 0.f, 0.f, 0.f};
    __builtin_amdgcn_s_setprio(1);
    QKT(Ks[0], s);
    __builtin_amdgcn_s_setprio(0);
    LDVR(VTs[0]);
    SMAX(s);
  }

  // region t (t>=1): barrier; DMA(t+1); QK^T(t) + PV(t-1) MFMA cluster;
  // reload vr = V(t); softmax(t) tail.
  auto REGION = [&](const _Float16* bK, const _Float16* bV,
                    _Float16* wK, _Float16* wV, int kvn, bool dodma) {
    __syncthreads();  // readers of wK/wV done; DMA(t) drained (vmcnt0)
    if (dodma) {
#pragma unroll
      for (int i = 0; i < 2; ++i) {
        gload_lds16(Kp + (size_t)(kvn + i * 32 + krow) * HD + kcol, &wK[(i * 256 + wv * 64) * 8]);
        gload_lds16(VTp + (size_t)(i * 32 + krow) * NSEQ + kvn + kcol, &wV[(i * 256 + wv * 64) * 8]);
      }
    }
    f16x8 ap[2][2];
    LDAP(ap);  // P(t-1), wave-private rows
    floatx4 s[2][4];
#pragma unroll
    for (int it = 0; it < 2; ++it)
#pragma unroll
      for (int im = 0; im < 4; ++im) s[it][im] = (floatx4){0.f, 0.f, 0.f, 0.f};
    __builtin_amdgcn_s_setprio(1);
    QKT(bK, s);
    PV(ap);  // consumes vr = V(t-1)
    __builtin_amdgcn_s_setprio(0);
    LDVR(bV);  // vr = V(t) for next region's PV
    SMAX(s);   // stores P(t); overlaps MFMA exec of this cluster
  };

#pragma unroll 1
  for (int p = 0; p < 31; ++p) {
    const int t0 = 2 * p + 1;
    REGION(Ks[1], VTs[1], Ks[0], VTs[0], (t0 + 1) * 64, true);
    REGION(Ks[0], VTs[0], Ks[1], VTs[1], (t0 + 2) * 64, true);
  }
  REGION(Ks[1], VTs[1], Ks[0], VTs[0], 0, false);  // t=63, no DMA
  // final PV(63): all wave-local (P in own rows, V in vr)
  {
    f16x8 ap[2][2];
    LDAP(ap);
    PV(ap);
  }

  // epilogue: full l per q (reduce over quads), broadcast to C-layout rows
#pragma unroll
  for (int it = 0; it < 2; ++it) {
    lp[it] += __shfl_xor(lp[it], 16);
    lp[it] += __shfl_xor(lp[it], 32);
  }
#pragma unroll
  for (int it = 0; it < 2; ++it)
#pragma unroll
    for (int r = 0; r < 4; ++r) {
      const int q = q0 + wv * 32 + it * 16 + quad * 4 + r;
      const float lq = __shfl(lp[it], (lane & 48) | (quad * 4 + r));
      const float inv = 1.0f / lq;
      _Float16* dst = ctx + (size_t)(bb * NSEQ + q) * DIMM + h * HD;
#pragma unroll
      for (int jn = 0; jn < 4; ++jn)
        dst[jn * 16 + l16] = (_Float16)(o[it][jn][r] * inv);
    }
}

extern "C" void kernel_launch(void* const* d_in, const int* in_sizes, int n_in,
                              void* d_out, int out_size, void* d_ws, size_t ws_size,
                              hipStream_t stream) {
  char* ws = (char*)d_ws;
  _Float16* xc = (_Float16*)ws;      ws += (size_t)8192 * 768 * 2;
  _Float16* wqkvT = (_Float16*)ws;   ws += (size_t)2304 * 768 * 2;
  _Float16* wprojT = (_Float16*)ws;  ws += (size_t)768 * 768 * 2;
  const size_t qkv_elems = (size_t)2 * NHEADS * NSEQ * HD;
  _Float16* Qb = (_Float16*)ws;      ws += qkv_elems * 2;
  _Float16* Kb = (_Float16*)ws;      ws += qkv_elems * 2;
  _Float16* Vb = (_Float16*)ws;      ws += qkv_elems * 2;
  _Float16* VTb = (_Float16*)ws;     ws += qkv_elems * 2;
  _Float16* ctx = xc;  // x dead after QKV GEMM; reuse as attention output

  const dim3 tb(32, 8, 1);
  const dim3 b256(256, 1, 1);
  hipLaunchKernelGGL(convert_f32_f16, dim3(3072, 1, 1), b256, 0, stream,
                     (const float4*)d_in[0], (f16x8*)xc, 8192 * 768 / 8);
  hipLaunchKernelGGL(transpose_f32_f16, dim3(72, 24, 1), tb, 0, stream,
                     (const float*)d_in[1], (uint16_t*)wqkvT, 768, 2304);
  hipLaunchKernelGGL(transpose_f32_f16, dim3(24, 24, 1), tb, 0, stream,
                     (const float*)d_in[3], (uint16_t*)wprojT, 768, 768);
  hipLaunchKernelGGL(gemm_bt, dim3(18, 64, 1), b256, 0, stream,
                     xc, wqkvT, (const float*)d_in[2], 768, 1, (void*)Qb, Kb, Vb);
  hipLaunchKernelGGL(transpose_b16, dim3(2, 128, 24), tb, 0, stream,
                     (const uint16_t*)Vb, (uint16_t*)VTb, 4096, 64);
  hipLaunchKernelGGL(attn, dim3(768, 1, 1), b256, 0, stream, Qb, Kb, VTb, ctx);
  hipLaunchKernelGGL(gemm_bt, dim3(6, 64, 1), b256, 0, stream,
                     ctx, wprojT, (const float*)d_in[4], 768, 0, d_out,
                     (_Float16*)nullptr, (_Float16*)nullptr);
}

// Round 6
// 274.636 us; speedup vs baseline: 1.3227x; 1.0422x over previous
//
#include <hip/hip_runtime.h>
#include <hip/hip_bf16.h>
#include <stdint.h>

typedef _Float16 f16x8 __attribute__((ext_vector_type(8)));
typedef _Float16 f16x4 __attribute__((ext_vector_type(4)));
typedef uint32_t u32x2 __attribute__((ext_vector_type(2)));
typedef float floatx4 __attribute__((ext_vector_type(4)));

#define NSEQ 4096
#define DIMM 768
#define NHEADS 12
#define HD 64

__device__ __forceinline__ void gload_lds16(const void* g, void* l) {
  typedef __attribute__((address_space(1))) const uint32_t GQ;
  typedef __attribute__((address_space(3))) uint32_t LQ;
  __builtin_amdgcn_global_load_lds((GQ*)g, (LQ*)l, 16, 0, 0);
}

__device__ __forceinline__ uint16_t f16_bits(float v) {
  _Float16 h = (_Float16)v;
  return __builtin_bit_cast(uint16_t, h);
}

// v_cvt_pkrtz_f16_f32: pack two f32 -> two f16 in one instruction
__device__ __forceinline__ uint32_t pkrtz(float a, float b) {
  return __builtin_bit_cast(uint32_t, __builtin_amdgcn_cvt_pkrtz(a, b));
}

// XOR-swizzled 64-elem-row tile: 16B unit u of row r lives at physical unit
// u ^ (r&7). Spreads (stride ≡ 0 mod 32 dwords) rows across all 32 banks.
__device__ __forceinline__ int swz(int row, int e) {
  return row * 64 + ((((e >> 3) ^ (row & 7)) << 3) | (e & 7));
}

// ---------------- fp32 -> f16 convert, 8 elems/thread -----------------------
__global__ __launch_bounds__(256) void convert_f32_f16(
    const float4* __restrict__ src, f16x8* __restrict__ dst, int n8) {
  const int i = blockIdx.x * 256 + threadIdx.x;
  if (i >= n8) return;
  const float4 a = src[2 * i], b = src[2 * i + 1];
  f16x8 o;
  o[0] = (_Float16)a.x; o[1] = (_Float16)a.y; o[2] = (_Float16)a.z; o[3] = (_Float16)a.w;
  o[4] = (_Float16)b.x; o[5] = (_Float16)b.y; o[6] = (_Float16)b.z; o[7] = (_Float16)b.w;
  dst[i] = o;
}

// ---------------- fused weight transpose+convert: both w_qkv and w_proj -----
// z=0: dst0[c][r] = f16(w0[r][c])  (768 x 2304)
// z=1: dst1[c][r] = f16(w1[r][c])  (768 x 768), blocks x>=24 idle
__global__ __launch_bounds__(256) void transpose_w(
    const float* __restrict__ w0, const float* __restrict__ w1,
    uint16_t* __restrict__ d0, uint16_t* __restrict__ d1) {
  __shared__ uint16_t tile[32][33];
  const int z = blockIdx.z;
  if (z && blockIdx.x >= 24) return;  // block-uniform early-out
  const float* src = z ? w1 : w0;
  uint16_t* dst = z ? d1 : d0;
  const int C = z ? 768 : 2304;
  const int R = 768;
  const int c0 = blockIdx.x * 32, r0 = blockIdx.y * 32;
  const int tx = threadIdx.x, ty = threadIdx.y;  // 32 x 8
#pragma unroll
  for (int i = 0; i < 32; i += 8)
    tile[ty + i][tx] = f16_bits(src[(size_t)(r0 + ty + i) * C + (c0 + tx)]);
  __syncthreads();
#pragma unroll
  for (int i = 0; i < 32; i += 8)
    dst[(size_t)(c0 + ty + i) * R + (r0 + tx)] = tile[tx][ty + i];
}

// ---------------- GEMM: C[m][n] = sum_k A[m][k] * Bt[n][k] + bias[n]
// 3-buffer counted-vmcnt pipeline (T4): STAGE(t+2) issued each iter, DMA
// stays in flight across barriers; vmcnt(4) drains only tile t's loads.
// mode 0: store FP32 to o0 row-major [M][768]
// mode 1: QKV scatter: Q->o0, K->o1 as [B,H,N,64] f16 (Q pre-scaled);
//         V->o2 TRANSPOSED as [B,H,64,N] f16 (kills the transpose_b16 pass;
//         r-loop walks consecutive n -> one packed f16x4 store per (i,j))
__global__ __launch_bounds__(256) void gemm_bt(
    const _Float16* __restrict__ A, const _Float16* __restrict__ Bt,
    const float* __restrict__ bias, int K, int mode,
    void* __restrict__ o0, _Float16* __restrict__ o1, _Float16* __restrict__ o2) {
  __shared__ __attribute__((aligned(16))) _Float16 As[3][128 * 32];
  __shared__ __attribute__((aligned(16))) _Float16 Bs[3][128 * 32];
  __shared__ float bias_s[128];
  const int tid = threadIdx.x;
  const int wv = tid >> 6;
  const int lane = tid & 63;
  const int quad = lane >> 4, l16 = lane & 15;
  const int wm = (wv >> 1) * 64, wn = (wv & 1) * 64;
  const int m0 = blockIdx.y * 128, n0 = blockIdx.x * 128;

  if (tid < 128) bias_s[tid] = bias[n0 + tid];

  floatx4 acc[4][4];
#pragma unroll
  for (int i = 0; i < 4; ++i)
#pragma unroll
    for (int j = 0; j < 4; ++j) acc[i][j] = (floatx4){0.f, 0.f, 0.f, 0.f};

  // DMA mapping: wave wv stages A/B tile rows [wv*32, wv*32+32).
  const int gr = lane >> 2, gc = (lane & 3) * 8;
  const _Float16* Ag = A + (size_t)(m0 + wv * 32 + gr) * K + gc;
  const _Float16* Bg = Bt + (size_t)(n0 + wv * 32 + gr) * K + gc;
  const size_t K16 = (size_t)16 * K;

  auto STAGE = [&](int buf, int kt) {
    _Float16* As0 = &As[buf][wv * 1024];
    _Float16* Bs0 = &Bs[buf][wv * 1024];
    gload_lds16(Ag + kt, As0);
    gload_lds16(Ag + kt + K16, As0 + 512);
    gload_lds16(Bg + kt, Bs0);
    gload_lds16(Bg + kt + K16, Bs0 + 512);
  };
  auto COMPUTE = [&](int buf) {
    f16x8 af[4], bfr[4];
#pragma unroll
    for (int i = 0; i < 4; ++i)
      af[i] = *(const f16x8*)&As[buf][(wm + i * 16 + l16) * 32 + quad * 8];
#pragma unroll
    for (int j = 0; j < 4; ++j)
      bfr[j] = *(const f16x8*)&Bs[buf][(wn + j * 16 + l16) * 32 + quad * 8];
    __builtin_amdgcn_s_setprio(1);
#pragma unroll
    for (int i = 0; i < 4; ++i)
#pragma unroll
      for (int j = 0; j < 4; ++j)
        acc[i][j] = __builtin_amdgcn_mfma_f32_16x16x32_f16(af[i], bfr[j], acc[i][j], 0, 0, 0);
    __builtin_amdgcn_s_setprio(0);
  };

  STAGE(0, 0);
  STAGE(1, 32);
  const int nt = K >> 5;
  int b0 = 0, b1 = 1, b2 = 2;
#pragma unroll 1
  for (int t = 0; t < nt - 2; ++t) {
    // tile t landed (its 4 loads are the oldest; 4 newer stay in flight)
    asm volatile("s_waitcnt vmcnt(4)" ::: "memory");
    __builtin_amdgcn_s_barrier();
    STAGE(b2, (t + 2) * 32);
    COMPUTE(b0);
    const int tmp = b0; b0 = b1; b1 = b2; b2 = tmp;
  }
  asm volatile("s_waitcnt vmcnt(4)" ::: "memory");
  __builtin_amdgcn_s_barrier();
  COMPUTE(b0);
  b0 = b1;
  asm volatile("s_waitcnt vmcnt(0)" ::: "memory");
  __builtin_amdgcn_s_barrier();
  COMPUTE(b0);

  if (mode == 0) {
    float* of = (float*)o0;
#pragma unroll
    for (int i = 0; i < 4; ++i)
#pragma unroll
      for (int j = 0; j < 4; ++j) {
        const int col = n0 + wn + j * 16 + l16;
        const float b = bias_s[wn + j * 16 + l16];
        const int mrow = m0 + wm + i * 16 + quad * 4;
#pragma unroll
        for (int r = 0; r < 4; ++r)
          of[(size_t)(mrow + r) * DIMM + col] = acc[i][j][r] + b;
      }
  } else {
    const int sec = n0 / DIMM;  // 0=Q 1=K 2=V
    if (sec < 2) {
      _Float16* dst = (sec == 0) ? (_Float16*)o0 : o1;
      const float sc = (sec == 0) ? 0.18033688011112042f : 1.0f;  // 1/8 * log2(e)
#pragma unroll
      for (int i = 0; i < 4; ++i)
#pragma unroll
        for (int j = 0; j < 4; ++j) {
          const int n = n0 + wn + j * 16 + l16;
          const int c = n - sec * DIMM;
          const int h = c >> 6, d = c & 63;
          const float b = bias_s[wn + j * 16 + l16];
          const int mrow = m0 + wm + i * 16 + quad * 4;
#pragma unroll
          for (int r = 0; r < 4; ++r) {
            const int m = mrow + r;
            const int bb = m >> 12, nr = m & 4095;
            dst[(((size_t)(bb * NHEADS + h)) * NSEQ + nr) * HD + d] =
                (_Float16)((acc[i][j][r] + b) * sc);
          }
        }
    } else {
      // V^T: o2[((bb*NHEADS+h)*HD + d)*NSEQ + nr], nr consecutive over r
#pragma unroll
      for (int i = 0; i < 4; ++i)
#pragma unroll
        for (int j = 0; j < 4; ++j) {
          const int c = n0 + wn + j * 16 + l16 - 2 * DIMM;
          const int h = c >> 6, d = c & 63;
          const float b = bias_s[wn + j * 16 + l16];
          const int mrow = m0 + wm + i * 16 + quad * 4;
          const int bb = mrow >> 12, nr = mrow & 4095;  // same bb for r=0..3
          f16x4 v;
#pragma unroll
          for (int r = 0; r < 4; ++r) v[r] = (_Float16)(acc[i][j][r] + b);
          *(f16x4*)&o2[(((size_t)(bb * NHEADS + h)) * HD + d) * NSEQ + nr] = v;
        }
    }
  }
}

// ---------------- flash attention v5: f16, S^T form, no-max exp2 softmax,
// pkrtz P-pack, XOR-swizzled LDS, setprio MFMA clusters, software-pipelined
// regions: region t computes QK^T(t) + PV(t-1) back-to-back; V(t) carried
// in registers across the barrier. -----------------------------------------
__global__ __launch_bounds__(256, 3) void attn(
    const _Float16* __restrict__ Qg, const _Float16* __restrict__ Kg,
    const _Float16* __restrict__ VTg, _Float16* __restrict__ ctx) {
  __shared__ __attribute__((aligned(16))) _Float16 Pt[128 * 64];  // Q stage / P^T
  __shared__ __attribute__((aligned(16))) _Float16 Ks[2][64 * 64];
  __shared__ __attribute__((aligned(16))) _Float16 VTs[2][64 * 64];
  const int tid = threadIdx.x;
  const int wv = tid >> 6, lane = tid & 63;
  const int quad = lane >> 4, l16 = lane & 15;
  // XCD swizzle: 768 blocks; id%8 = XCD -> each XCD owns 3 bh (K/V L2-resident)
  const int bi = blockIdx.x;
  const int xcd = bi & 7, j = bi >> 3;
  const int bh = xcd * 3 + (j >> 5);
  const int q0 = (j & 31) * 128;
  const int bb = bh / NHEADS, h = bh - bb * NHEADS;
  const _Float16* Qp = Qg + (size_t)bh * NSEQ * HD;
  const _Float16* Kp = Kg + (size_t)bh * NSEQ * HD;
  const _Float16* VTp = VTg + (size_t)bh * HD * NSEQ;

  const int krow = tid >> 3;
  // DMA lane->global-unit permute implements the XOR swizzle
  const int kcol = (((tid & 7) ^ ((tid >> 3) & 7)) * 8);
  const int l7 = l16 & 7;

  // preamble: DMA Q tile [128][64] into Pt area + KV tile 0 into buf0
#pragma unroll
  for (int i = 0; i < 4; ++i)
    gload_lds16(Qp + (size_t)(q0 + i * 32 + krow) * HD + kcol, &Pt[(i * 256 + wv * 64) * 8]);
#pragma unroll
  for (int i = 0; i < 2; ++i) {
    gload_lds16(Kp + (size_t)(i * 32 + krow) * HD + kcol, &Ks[0][(i * 256 + wv * 64) * 8]);
    gload_lds16(VTp + (size_t)(i * 32 + krow) * NSEQ + kcol, &VTs[0][(i * 256 + wv * 64) * 8]);
  }
  __syncthreads();  // drains DMA: Q + buf0 visible

  f16x8 aq[2][2];
#pragma unroll
  for (int it = 0; it < 2; ++it)
#pragma unroll
    for (int ks = 0; ks < 2; ++ks)
      aq[it][ks] = *(const f16x8*)&Pt[swz(wv * 32 + it * 16 + l16, ks * 32 + quad * 8)];

  // issue DMA tile1 -> buf1 (drained at the first loop barrier)
#pragma unroll
  for (int i = 0; i < 2; ++i) {
    gload_lds16(Kp + (size_t)(64 + i * 32 + krow) * HD + kcol, &Ks[1][(i * 256 + wv * 64) * 8]);
    gload_lds16(VTp + (size_t)(i * 32 + krow) * NSEQ + 64 + kcol, &VTs[1][(i * 256 + wv * 64) * 8]);
  }

  floatx4 o[2][4];
  float lp[2] = {0.f, 0.f};
#pragma unroll
  for (int it = 0; it < 2; ++it)
#pragma unroll
    for (int jn = 0; jn < 4; ++jn) o[it][jn] = (floatx4){0.f, 0.f, 0.f, 0.f};

  const int prow = wv * 32 + l16;
  f16x8 vr[2][4];  // V(t) fragments carried across the barrier

  // S^T = K . Q^T  (exp2-domain: Q pre-scaled by 0.125*log2e)
  auto QKT = [&](const _Float16* bK, floatx4 (&s)[2][4]) {
#pragma unroll
    for (int ks = 0; ks < 2; ++ks) {
#pragma unroll
      for (int im = 0; im < 4; ++im) {
        const f16x8 bk = *(const f16x8*)&bK[swz(im * 16 + l16, ks * 32 + quad * 8)];
        s[0][im] = __builtin_amdgcn_mfma_f32_16x16x32_f16(bk, aq[0][ks], s[0][im], 0, 0, 0);
        s[1][im] = __builtin_amdgcn_mfma_f32_16x16x32_f16(bk, aq[1][ks], s[1][im], 0, 0, 0);
      }
    }
  };
  auto LDVR = [&](const _Float16* bV) {
#pragma unroll
    for (int kk = 0; kk < 2; ++kk)
#pragma unroll
      for (int jn = 0; jn < 4; ++jn)
        vr[kk][jn] = *(const f16x8*)&bV[swz(jn * 16 + l16, kk * 32 + quad * 8)];
  };
  // p = exp2(s); per-lane partial l; pack via native pkrtz; b64 P^T stores
  auto SMAX = [&](floatx4 (&s)[2][4]) {
#pragma unroll
    for (int it = 0; it < 2; ++it) {
      const int row = prow + it * 16;
#pragma unroll
      for (int im = 0; im < 4; ++im) {
        float p0 = __builtin_amdgcn_exp2f(s[it][im][0]);
        float p1 = __builtin_amdgcn_exp2f(s[it][im][1]);
        float p2 = __builtin_amdgcn_exp2f(s[it][im][2]);
        float p3 = __builtin_amdgcn_exp2f(s[it][im][3]);
        lp[it] += (p0 + p1) + (p2 + p3);
        const u32x2 packed = {pkrtz(p0, p1), pkrtz(p2, p3)};
        *(f16x4*)&Pt[row * 64 + (((im * 2 + (quad >> 1)) ^ l7) << 3) + (quad & 1) * 4] =
            __builtin_bit_cast(f16x4, packed);
      }
    }
  };
  auto LDAP = [&](f16x8 (&ap)[2][2]) {
#pragma unroll
    for (int kk = 0; kk < 2; ++kk) {
      ap[kk][0] = *(const f16x8*)&Pt[swz(prow, kk * 32 + quad * 8)];
      ap[kk][1] = *(const f16x8*)&Pt[swz(prow + 16, kk * 32 + quad * 8)];
    }
  };
  auto PV = [&](const f16x8 (&ap)[2][2]) {
#pragma unroll
    for (int kk = 0; kk < 2; ++kk) {
#pragma unroll
      for (int jn = 0; jn < 4; ++jn) {
        o[0][jn] = __builtin_amdgcn_mfma_f32_16x16x32_f16(ap[kk][0], vr[kk][jn], o[0][jn], 0, 0, 0);
        o[1][jn] = __builtin_amdgcn_mfma_f32_16x16x32_f16(ap[kk][1], vr[kk][jn], o[1][jn], 0, 0, 0);
      }
    }
  };

  // region 0 (no PV): QK^T(0), stash V(0) in regs, softmax(0) -> P(0)
  {
    floatx4 s[2][4];
#pragma unroll
    for (int it = 0; it < 2; ++it)
#pragma unroll
      for (int im = 0; im < 4; ++im) s[it][im] = (floatx4){0.f, 0.f, 0.f, 0.f};
    __builtin_amdgcn_s_setprio(1);
    QKT(Ks[0], s);
    __builtin_amdgcn_s_setprio(0);
    LDVR(VTs[0]);
    SMAX(s);
  }

  // region t (t>=1): barrier; DMA(t+1); QK^T(t) + PV(t-1) MFMA cluster;
  // reload vr = V(t); softmax(t) tail.
  auto REGION = [&](const _Float16* bK, const _Float16* bV,
                    _Float16* wK, _Float16* wV, int kvn, bool dodma) {
    __syncthreads();  // readers of wK/wV done; DMA(t) drained (vmcnt0)
    if (dodma) {
#pragma unroll
      for (int i = 0; i < 2; ++i) {
        gload_lds16(Kp + (size_t)(kvn + i * 32 + krow) * HD + kcol, &wK[(i * 256 + wv * 64) * 8]);
        gload_lds16(VTp + (size_t)(i * 32 + krow) * NSEQ + kvn + kcol, &wV[(i * 256 + wv * 64) * 8]);
      }
    }
    f16x8 ap[2][2];
    LDAP(ap);  // P(t-1), wave-private rows
    floatx4 s[2][4];
#pragma unroll
    for (int it = 0; it < 2; ++it)
#pragma unroll
      for (int im = 0; im < 4; ++im) s[it][im] = (floatx4){0.f, 0.f, 0.f, 0.f};
    __builtin_amdgcn_s_setprio(1);
    QKT(bK, s);
    PV(ap);  // consumes vr = V(t-1)
    __builtin_amdgcn_s_setprio(0);
    LDVR(bV);  // vr = V(t) for next region's PV
    SMAX(s);   // stores P(t); overlaps MFMA exec of this cluster
  };

#pragma unroll 1
  for (int p = 0; p < 31; ++p) {
    const int t0 = 2 * p + 1;
    REGION(Ks[1], VTs[1], Ks[0], VTs[0], (t0 + 1) * 64, true);
    REGION(Ks[0], VTs[0], Ks[1], VTs[1], (t0 + 2) * 64, true);
  }
  REGION(Ks[1], VTs[1], Ks[0], VTs[0], 0, false);  // t=63, no DMA
  // final PV(63): all wave-local (P in own rows, V in vr)
  {
    f16x8 ap[2][2];
    LDAP(ap);
    PV(ap);
  }

  // epilogue: full l per q (reduce over quads), broadcast to C-layout rows
#pragma unroll
  for (int it = 0; it < 2; ++it) {
    lp[it] += __shfl_xor(lp[it], 16);
    lp[it] += __shfl_xor(lp[it], 32);
  }
#pragma unroll
  for (int it = 0; it < 2; ++it)
#pragma unroll
    for (int r = 0; r < 4; ++r) {
      const int q = q0 + wv * 32 + it * 16 + quad * 4 + r;
      const float lq = __shfl(lp[it], (lane & 48) | (quad * 4 + r));
      const float inv = 1.0f / lq;
      _Float16* dst = ctx + (size_t)(bb * NSEQ + q) * DIMM + h * HD;
#pragma unroll
      for (int jn = 0; jn < 4; ++jn)
        dst[jn * 16 + l16] = (_Float16)(o[it][jn][r] * inv);
    }
}

extern "C" void kernel_launch(void* const* d_in, const int* in_sizes, int n_in,
                              void* d_out, int out_size, void* d_ws, size_t ws_size,
                              hipStream_t stream) {
  char* ws = (char*)d_ws;
  _Float16* xc = (_Float16*)ws;      ws += (size_t)8192 * 768 * 2;
  _Float16* wqkvT = (_Float16*)ws;   ws += (size_t)2304 * 768 * 2;
  _Float16* wprojT = (_Float16*)ws;  ws += (size_t)768 * 768 * 2;
  const size_t qkv_elems = (size_t)2 * NHEADS * NSEQ * HD;
  _Float16* Qb = (_Float16*)ws;      ws += qkv_elems * 2;
  _Float16* Kb = (_Float16*)ws;      ws += qkv_elems * 2;
  _Float16* VTb = (_Float16*)ws;     ws += qkv_elems * 2;
  _Float16* ctx = xc;  // x dead after QKV GEMM; reuse as attention output

  const dim3 tb(32, 8, 1);
  const dim3 b256(256, 1, 1);
  hipLaunchKernelGGL(convert_f32_f16, dim3(3072, 1, 1), b256, 0, stream,
                     (const float4*)d_in[0], (f16x8*)xc, 8192 * 768 / 8);
  hipLaunchKernelGGL(transpose_w, dim3(72, 24, 2), tb, 0, stream,
                     (const float*)d_in[1], (const float*)d_in[3],
                     (uint16_t*)wqkvT, (uint16_t*)wprojT);
  hipLaunchKernelGGL(gemm_bt, dim3(18, 64, 1), b256, 0, stream,
                     xc, wqkvT, (const float*)d_in[2], 768, 1, (void*)Qb, Kb, VTb);
  hipLaunchKernelGGL(attn, dim3(768, 1, 1), b256, 0, stream, Qb, Kb, VTb, ctx);
  hipLaunchKernelGGL(gemm_bt, dim3(6, 64, 1), b256, 0, stream,
                     ctx, wprojT, (const float*)d_in[4], 768, 0, d_out,
                     (_Float16*)nullptr, (_Float16*)nullptr);
}

// Round 7
// 271.278 us; speedup vs baseline: 1.3391x; 1.0124x over previous
//
#include <hip/hip_runtime.h>
#include <hip/hip_bf16.h>
#include <stdint.h>

typedef _Float16 f16x8 __attribute__((ext_vector_type(8)));
typedef _Float16 f16x4 __attribute__((ext_vector_type(4)));
typedef uint32_t u32x2 __attribute__((ext_vector_type(2)));
typedef uint32_t u32x4 __attribute__((ext_vector_type(4)));
typedef float floatx4 __attribute__((ext_vector_type(4)));

#define NSEQ 4096
#define DIMM 768
#define NHEADS 12
#define HD 64

__device__ __forceinline__ void gload_lds16(const void* g, void* l) {
  typedef __attribute__((address_space(1))) const uint32_t GQ;
  typedef __attribute__((address_space(3))) uint32_t LQ;
  __builtin_amdgcn_global_load_lds((GQ*)g, (LQ*)l, 16, 0, 0);
}

__device__ __forceinline__ uint16_t f16_bits(float v) {
  _Float16 h = (_Float16)v;
  return __builtin_bit_cast(uint16_t, h);
}

// v_cvt_pkrtz_f16_f32: pack two f32 -> two f16 in one instruction
__device__ __forceinline__ uint32_t pkrtz(float a, float b) {
  return __builtin_bit_cast(uint32_t, __builtin_amdgcn_cvt_pkrtz(a, b));
}

// XOR-swizzled 64-elem-row tile: 16B unit u of row r lives at physical unit
// u ^ (r&7). Spreads (stride ≡ 0 mod 32 dwords) rows across all 32 banks.
__device__ __forceinline__ int swz(int row, int e) {
  return row * 64 + ((((e >> 3) ^ (row & 7)) << 3) | (e & 7));
}

// ---------------- fp32 -> f16 convert, 8 elems/thread -----------------------
__global__ __launch_bounds__(256) void convert_f32_f16(
    const float4* __restrict__ src, f16x8* __restrict__ dst, int n8) {
  const int i = blockIdx.x * 256 + threadIdx.x;
  if (i >= n8) return;
  const float4 a = src[2 * i], b = src[2 * i + 1];
  f16x8 o;
  o[0] = (_Float16)a.x; o[1] = (_Float16)a.y; o[2] = (_Float16)a.z; o[3] = (_Float16)a.w;
  o[4] = (_Float16)b.x; o[5] = (_Float16)b.y; o[6] = (_Float16)b.z; o[7] = (_Float16)b.w;
  dst[i] = o;
}

// ---------------- fused weight transpose+convert: both w_qkv and w_proj -----
// z=0: dst0[c][r] = f16(w0[r][c])  (768 x 2304)
// z=1: dst1[c][r] = f16(w1[r][c])  (768 x 768), blocks x>=24 idle
__global__ __launch_bounds__(256) void transpose_w(
    const float* __restrict__ w0, const float* __restrict__ w1,
    uint16_t* __restrict__ d0, uint16_t* __restrict__ d1) {
  __shared__ uint16_t tile[32][33];
  const int z = blockIdx.z;
  if (z && blockIdx.x >= 24) return;  // block-uniform early-out
  const float* src = z ? w1 : w0;
  uint16_t* dst = z ? d1 : d0;
  const int C = z ? 768 : 2304;
  const int R = 768;
  const int c0 = blockIdx.x * 32, r0 = blockIdx.y * 32;
  const int tx = threadIdx.x, ty = threadIdx.y;  // 32 x 8
#pragma unroll
  for (int i = 0; i < 32; i += 8)
    tile[ty + i][tx] = f16_bits(src[(size_t)(r0 + ty + i) * C + (c0 + tx)]);
  __syncthreads();
#pragma unroll
  for (int i = 0; i < 32; i += 8)
    dst[(size_t)(c0 + ty + i) * R + (r0 + tx)] = tile[tx][ty + i];
}

// ---------------- GEMM: C[m][n] = sum_k A[m][k] * Bt[n][k] + bias[n]
// 3-buffer counted-vmcnt pipeline (T4): STAGE(t+2) issued each iter, DMA
// stays in flight across barriers; vmcnt(4) drains only tile t's loads.
// mode 0: store FP32 to o0 row-major [M][768]
// mode 1: QKV scatter: Q->o0, K->o1 as [B,H,N,64] f16 (Q pre-scaled);
//         V->o2 TRANSPOSED as [B,H,64,N] f16
__global__ __launch_bounds__(256) void gemm_bt(
    const _Float16* __restrict__ A, const _Float16* __restrict__ Bt,
    const float* __restrict__ bias, int K, int mode,
    void* __restrict__ o0, _Float16* __restrict__ o1, _Float16* __restrict__ o2) {
  __shared__ __attribute__((aligned(16))) _Float16 As[3][128 * 32];
  __shared__ __attribute__((aligned(16))) _Float16 Bs[3][128 * 32];
  __shared__ float bias_s[128];
  const int tid = threadIdx.x;
  const int wv = tid >> 6;
  const int lane = tid & 63;
  const int quad = lane >> 4, l16 = lane & 15;
  const int wm = (wv >> 1) * 64, wn = (wv & 1) * 64;
  const int m0 = blockIdx.y * 128, n0 = blockIdx.x * 128;

  if (tid < 128) bias_s[tid] = bias[n0 + tid];

  floatx4 acc[4][4];
#pragma unroll
  for (int i = 0; i < 4; ++i)
#pragma unroll
    for (int j = 0; j < 4; ++j) acc[i][j] = (floatx4){0.f, 0.f, 0.f, 0.f};

  // DMA mapping: wave wv stages A/B tile rows [wv*32, wv*32+32).
  const int gr = lane >> 2, gc = (lane & 3) * 8;
  const _Float16* Ag = A + (size_t)(m0 + wv * 32 + gr) * K + gc;
  const _Float16* Bg = Bt + (size_t)(n0 + wv * 32 + gr) * K + gc;
  const size_t K16 = (size_t)16 * K;

  auto STAGE = [&](int buf, int kt) {
    _Float16* As0 = &As[buf][wv * 1024];
    _Float16* Bs0 = &Bs[buf][wv * 1024];
    gload_lds16(Ag + kt, As0);
    gload_lds16(Ag + kt + K16, As0 + 512);
    gload_lds16(Bg + kt, Bs0);
    gload_lds16(Bg + kt + K16, Bs0 + 512);
  };
  auto COMPUTE = [&](int buf) {
    f16x8 af[4], bfr[4];
#pragma unroll
    for (int i = 0; i < 4; ++i)
      af[i] = *(const f16x8*)&As[buf][(wm + i * 16 + l16) * 32 + quad * 8];
#pragma unroll
    for (int j = 0; j < 4; ++j)
      bfr[j] = *(const f16x8*)&Bs[buf][(wn + j * 16 + l16) * 32 + quad * 8];
    __builtin_amdgcn_s_setprio(1);
#pragma unroll
    for (int i = 0; i < 4; ++i)
#pragma unroll
      for (int j = 0; j < 4; ++j)
        acc[i][j] = __builtin_amdgcn_mfma_f32_16x16x32_f16(af[i], bfr[j], acc[i][j], 0, 0, 0);
    __builtin_amdgcn_s_setprio(0);
  };

  STAGE(0, 0);
  STAGE(1, 32);
  const int nt = K >> 5;
  int b0 = 0, b1 = 1, b2 = 2;
#pragma unroll 1
  for (int t = 0; t < nt - 2; ++t) {
    // tile t landed (its 4 loads are the oldest; 4 newer stay in flight)
    asm volatile("s_waitcnt vmcnt(4)" ::: "memory");
    __builtin_amdgcn_s_barrier();
    STAGE(b2, (t + 2) * 32);
    COMPUTE(b0);
    const int tmp = b0; b0 = b1; b1 = b2; b2 = tmp;
  }
  asm volatile("s_waitcnt vmcnt(4)" ::: "memory");
  __builtin_amdgcn_s_barrier();
  COMPUTE(b0);
  b0 = b1;
  asm volatile("s_waitcnt vmcnt(0)" ::: "memory");
  __builtin_amdgcn_s_barrier();
  COMPUTE(b0);

  if (mode == 0) {
    float* of = (float*)o0;
#pragma unroll
    for (int i = 0; i < 4; ++i)
#pragma unroll
      for (int j = 0; j < 4; ++j) {
        const int col = n0 + wn + j * 16 + l16;
        const float b = bias_s[wn + j * 16 + l16];
        const int mrow = m0 + wm + i * 16 + quad * 4;
#pragma unroll
        for (int r = 0; r < 4; ++r)
          of[(size_t)(mrow + r) * DIMM + col] = acc[i][j][r] + b;
      }
  } else {
    const int sec = n0 / DIMM;  // 0=Q 1=K 2=V
    if (sec < 2) {
      _Float16* dst = (sec == 0) ? (_Float16*)o0 : o1;
      const float sc = (sec == 0) ? 0.18033688011112042f : 1.0f;  // 1/8 * log2(e)
#pragma unroll
      for (int i = 0; i < 4; ++i)
#pragma unroll
        for (int j = 0; j < 4; ++j) {
          const int n = n0 + wn + j * 16 + l16;
          const int c = n - sec * DIMM;
          const int h = c >> 6, d = c & 63;
          const float b = bias_s[wn + j * 16 + l16];
          const int mrow = m0 + wm + i * 16 + quad * 4;
#pragma unroll
          for (int r = 0; r < 4; ++r) {
            const int m = mrow + r;
            const int bb = m >> 12, nr = m & 4095;
            dst[(((size_t)(bb * NHEADS + h)) * NSEQ + nr) * HD + d] =
                (_Float16)((acc[i][j][r] + b) * sc);
          }
        }
    } else {
      // V^T: o2[((bb*NHEADS+h)*HD + d)*NSEQ + nr], nr consecutive over r
#pragma unroll
      for (int i = 0; i < 4; ++i)
#pragma unroll
        for (int j = 0; j < 4; ++j) {
          const int c = n0 + wn + j * 16 + l16 - 2 * DIMM;
          const int h = c >> 6, d = c & 63;
          const float b = bias_s[wn + j * 16 + l16];
          const int mrow = m0 + wm + i * 16 + quad * 4;
          const int bb = mrow >> 12, nr = mrow & 4095;  // same bb for r=0..3
          f16x4 v;
#pragma unroll
          for (int r = 0; r < 4; ++r) v[r] = (_Float16)(acc[i][j][r] + b);
          *(f16x4*)&o2[(((size_t)(bb * NHEADS + h)) * HD + d) * NSEQ + nr] = v;
        }
    }
  }
}

// ---------------- flash attention v7: P NEVER TOUCHES LDS. QK^T's C-layout
// (P[q=l16][k=im*16+quad*4+r]) is permuted to PV's A-layout
// (P[q=l16][k=kk*32+quad*8+j]) in-register via gfx950 v_permlane16/32_swap
// (VALU pipe), deleting 8 ds_write_b64 + 4 ds_read_b128 per wave-region
// (12/28 of all LDS ops). Memory/barrier schedule identical to v5. ----------
__global__ __launch_bounds__(256, 3) void attn(
    const _Float16* __restrict__ Qg, const _Float16* __restrict__ Kg,
    const _Float16* __restrict__ VTg, _Float16* __restrict__ ctx) {
  __shared__ __attribute__((aligned(16))) _Float16 Pt[128 * 64];  // Q stage
  __shared__ __attribute__((aligned(16))) _Float16 Ks[2][64 * 64];
  __shared__ __attribute__((aligned(16))) _Float16 VTs[2][64 * 64];
  const int tid = threadIdx.x;
  const int wv = tid >> 6, lane = tid & 63;
  const int quad = lane >> 4, l16 = lane & 15;
  // XCD swizzle: 768 blocks; id%8 = XCD -> each XCD owns 3 bh (K/V L2-resident)
  const int bi = blockIdx.x;
  const int xcd = bi & 7, j = bi >> 3;
  const int bh = xcd * 3 + (j >> 5);
  const int q0 = (j & 31) * 128;
  const int bb = bh / NHEADS, h = bh - bb * NHEADS;
  const _Float16* Qp = Qg + (size_t)bh * NSEQ * HD;
  const _Float16* Kp = Kg + (size_t)bh * NSEQ * HD;
  const _Float16* VTp = VTg + (size_t)bh * HD * NSEQ;

  const int krow = tid >> 3;
  // DMA lane->global-unit permute implements the XOR swizzle
  const int kcol = (((tid & 7) ^ ((tid >> 3) & 7)) * 8);

  // preamble: DMA Q tile [128][64] into Pt area + KV tile 0 into buf0
#pragma unroll
  for (int i = 0; i < 4; ++i)
    gload_lds16(Qp + (size_t)(q0 + i * 32 + krow) * HD + kcol, &Pt[(i * 256 + wv * 64) * 8]);
#pragma unroll
  for (int i = 0; i < 2; ++i) {
    gload_lds16(Kp + (size_t)(i * 32 + krow) * HD + kcol, &Ks[0][(i * 256 + wv * 64) * 8]);
    gload_lds16(VTp + (size_t)(i * 32 + krow) * NSEQ + kcol, &VTs[0][(i * 256 + wv * 64) * 8]);
  }
  __syncthreads();  // drains DMA: Q + buf0 visible

  f16x8 aq[2][2];
#pragma unroll
  for (int it = 0; it < 2; ++it)
#pragma unroll
    for (int ks = 0; ks < 2; ++ks)
      aq[it][ks] = *(const f16x8*)&Pt[swz(wv * 32 + it * 16 + l16, ks * 32 + quad * 8)];

  // issue DMA tile1 -> buf1 (drained at the first loop barrier)
#pragma unroll
  for (int i = 0; i < 2; ++i) {
    gload_lds16(Kp + (size_t)(64 + i * 32 + krow) * HD + kcol, &Ks[1][(i * 256 + wv * 64) * 8]);
    gload_lds16(VTp + (size_t)(i * 32 + krow) * NSEQ + 64 + kcol, &VTs[1][(i * 256 + wv * 64) * 8]);
  }

  floatx4 o[2][4];
  float lp[2] = {0.f, 0.f};
#pragma unroll
  for (int it = 0; it < 2; ++it)
#pragma unroll
    for (int jn = 0; jn < 4; ++jn) o[it][jn] = (floatx4){0.f, 0.f, 0.f, 0.f};

  f16x8 vr[2][4];   // V(t) fragments carried across the barrier
  f16x8 ap[2][2];   // P(t) A-fragments, built in-register by SMAX

  // S^T = K . Q^T  (exp2-domain: Q pre-scaled by 0.125*log2e)
  auto QKT = [&](const _Float16* bK, floatx4 (&s)[2][4]) {
#pragma unroll
    for (int ks = 0; ks < 2; ++ks) {
#pragma unroll
      for (int im = 0; im < 4; ++im) {
        const f16x8 bk = *(const f16x8*)&bK[swz(im * 16 + l16, ks * 32 + quad * 8)];
        s[0][im] = __builtin_amdgcn_mfma_f32_16x16x32_f16(bk, aq[0][ks], s[0][im], 0, 0, 0);
        s[1][im] = __builtin_amdgcn_mfma_f32_16x16x32_f16(bk, aq[1][ks], s[1][im], 0, 0, 0);
      }
    }
  };
  auto LDVR = [&](const _Float16* bV) {
#pragma unroll
    for (int kk = 0; kk < 2; ++kk)
#pragma unroll
      for (int jn = 0; jn < 4; ++jn)
        vr[kk][jn] = *(const f16x8*)&bV[swz(jn * 16 + l16, kk * 32 + quad * 8)];
  };
  // p = exp2(s); per-lane partial l; pkrtz pack; permlane quad-redistribute
  // C-layout -> A-layout entirely in registers (no LDS).
  auto SMAX = [&](floatx4 (&s)[2][4]) {
#pragma unroll
    for (int it = 0; it < 2; ++it) {
      uint32_t w[4][2];
#pragma unroll
      for (int im = 0; im < 4; ++im) {
        float p0 = __builtin_amdgcn_exp2f(s[it][im][0]);
        float p1 = __builtin_amdgcn_exp2f(s[it][im][1]);
        float p2 = __builtin_amdgcn_exp2f(s[it][im][2]);
        float p3 = __builtin_amdgcn_exp2f(s[it][im][3]);
        lp[it] += (p0 + p1) + (p2 + p3);
        w[im][0] = pkrtz(p0, p1);
        w[im][1] = pkrtz(p2, p3);
      }
      // redistribute: target quad qt needs W[2kk+(qt>>1)][hi] from source
      // quads (qt&1)*2 + s1.  permlane32 then permlane16 on (even-im, odd-im)
      // pairs produces exactly A-fragment words [slot0..slot3].
#pragma unroll
      for (int kk = 0; kk < 2; ++kk) {
        uint32_t a = w[2 * kk][0], c = w[2 * kk + 1][0];
        uint32_t b = w[2 * kk][1], d = w[2 * kk + 1][1];
        asm("v_permlane32_swap_b32 %0, %1" : "+v"(a), "+v"(c));
        asm("v_permlane16_swap_b32 %0, %1" : "+v"(a), "+v"(c));
        asm("v_permlane32_swap_b32 %0, %1" : "+v"(b), "+v"(d));
        asm("v_permlane16_swap_b32 %0, %1" : "+v"(b), "+v"(d));
        const u32x4 pk = {a, b, c, d};
        ap[kk][it] = __builtin_bit_cast(f16x8, pk);
      }
    }
  };
  auto PV = [&]() {
#pragma unroll
    for (int kk = 0; kk < 2; ++kk) {
#pragma unroll
      for (int jn = 0; jn < 4; ++jn) {
        o[0][jn] = __builtin_amdgcn_mfma_f32_16x16x32_f16(ap[kk][0], vr[kk][jn], o[0][jn], 0, 0, 0);
        o[1][jn] = __builtin_amdgcn_mfma_f32_16x16x32_f16(ap[kk][1], vr[kk][jn], o[1][jn], 0, 0, 0);
      }
    }
  };

  // region 0 (no PV): QK^T(0), stash V(0) in regs, softmax(0) -> ap
  {
    floatx4 s[2][4];
#pragma unroll
    for (int it = 0; it < 2; ++it)
#pragma unroll
      for (int im = 0; im < 4; ++im) s[it][im] = (floatx4){0.f, 0.f, 0.f, 0.f};
    __builtin_amdgcn_s_setprio(1);
    QKT(Ks[0], s);
    __builtin_amdgcn_s_setprio(0);
    LDVR(VTs[0]);
    SMAX(s);
  }

  // region t (t>=1): barrier; DMA(t+1); QK^T(t) + PV(t-1) MFMA cluster;
  // reload vr = V(t); softmax(t) -> ap (in-register) tail.
  auto REGION = [&](const _Float16* bK, const _Float16* bV,
                    _Float16* wK, _Float16* wV, int kvn, bool dodma) {
    __syncthreads();  // readers of wK/wV done; DMA(t) drained (vmcnt0)
    if (dodma) {
#pragma unroll
      for (int i = 0; i < 2; ++i) {
        gload_lds16(Kp + (size_t)(kvn + i * 32 + krow) * HD + kcol, &wK[(i * 256 + wv * 64) * 8]);
        gload_lds16(VTp + (size_t)(i * 32 + krow) * NSEQ + kvn + kcol, &wV[(i * 256 + wv * 64) * 8]);
      }
    }
    floatx4 s[2][4];
#pragma unroll
    for (int it = 0; it < 2; ++it)
#pragma unroll
      for (int im = 0; im < 4; ++im) s[it][im] = (floatx4){0.f, 0.f, 0.f, 0.f};
    __builtin_amdgcn_s_setprio(1);
    QKT(bK, s);
    PV();      // consumes ap,vr = region t-1
    __builtin_amdgcn_s_setprio(0);
    LDVR(bV);  // vr = V(t) for next region's PV
    SMAX(s);   // ap = P(t) in-register
  };

#pragma unroll 1
  for (int p = 0; p < 31; ++p) {
    const int t0 = 2 * p + 1;
    REGION(Ks[1], VTs[1], Ks[0], VTs[0], (t0 + 1) * 64, true);
    REGION(Ks[0], VTs[0], Ks[1], VTs[1], (t0 + 2) * 64, true);
  }
  REGION(Ks[1], VTs[1], Ks[0], VTs[0], 0, false);  // t=63, no DMA
  PV();  // final PV(63): all in-register

  // epilogue: full l per q (reduce over quads), broadcast to C-layout rows
#pragma unroll
  for (int it = 0; it < 2; ++it) {
    lp[it] += __shfl_xor(lp[it], 16);
    lp[it] += __shfl_xor(lp[it], 32);
  }
#pragma unroll
  for (int it = 0; it < 2; ++it)
#pragma unroll
    for (int r = 0; r < 4; ++r) {
      const int q = q0 + wv * 32 + it * 16 + quad * 4 + r;
      const float lq = __shfl(lp[it], (lane & 48) | (quad * 4 + r));
      const float inv = 1.0f / lq;
      _Float16* dst = ctx + (size_t)(bb * NSEQ + q) * DIMM + h * HD;
#pragma unroll
      for (int jn = 0; jn < 4; ++jn)
        dst[jn * 16 + l16] = (_Float16)(o[it][jn][r] * inv);
    }
}

extern "C" void kernel_launch(void* const* d_in, const int* in_sizes, int n_in,
                              void* d_out, int out_size, void* d_ws, size_t ws_size,
                              hipStream_t stream) {
  char* ws = (char*)d_ws;
  _Float16* xc = (_Float16*)ws;      ws += (size_t)8192 * 768 * 2;
  _Float16* wqkvT = (_Float16*)ws;   ws += (size_t)2304 * 768 * 2;
  _Float16* wprojT = (_Float16*)ws;  ws += (size_t)768 * 768 * 2;
  const size_t qkv_elems = (size_t)2 * NHEADS * NSEQ * HD;
  _Float16* Qb = (_Float16*)ws;      ws += qkv_elems * 2;
  _Float16* Kb = (_Float16*)ws;      ws += qkv_elems * 2;
  _Float16* VTb = (_Float16*)ws;     ws += qkv_elems * 2;
  _Float16* ctx = xc;  // x dead after QKV GEMM; reuse as attention output

  const dim3 tb(32, 8, 1);
  const dim3 b256(256, 1, 1);
  hipLaunchKernelGGL(convert_f32_f16, dim3(3072, 1, 1), b256, 0, stream,
                     (const float4*)d_in[0], (f16x8*)xc, 8192 * 768 / 8);
  hipLaunchKernelGGL(transpose_w, dim3(72, 24, 2), tb, 0, stream,
                     (const float*)d_in[1], (const float*)d_in[3],
                     (uint16_t*)wqkvT, (uint16_t*)wprojT);
  hipLaunchKernelGGL(gemm_bt, dim3(18, 64, 1), b256, 0, stream,
                     xc, wqkvT, (const float*)d_in[2], 768, 1, (void*)Qb, Kb, VTb);
  hipLaunchKernelGGL(attn, dim3(768, 1, 1), b256, 0, stream, Qb, Kb, VTb, ctx);
  hipLaunchKernelGGL(gemm_bt, dim3(6, 64, 1), b256, 0, stream,
                     ctx, wprojT, (const float*)d_in[4], 768, 0, d_out,
                     (_Float16*)nullptr, (_Float16*)nullptr);
}

// Round 8
// 265.892 us; speedup vs baseline: 1.3662x; 1.0203x over previous
//
#include <hip/hip_runtime.h>
#include <hip/hip_bf16.h>
#include <stdint.h>

typedef _Float16 f16x8 __attribute__((ext_vector_type(8)));
typedef _Float16 f16x4 __attribute__((ext_vector_type(4)));
typedef uint32_t u32x2 __attribute__((ext_vector_type(2)));
typedef uint32_t u32x4 __attribute__((ext_vector_type(4)));
typedef float floatx4 __attribute__((ext_vector_type(4)));

#define NSEQ 4096
#define DIMM 768
#define NHEADS 12
#define HD 64

__device__ __forceinline__ void gload_lds16(const void* g, void* l) {
  typedef __attribute__((address_space(1))) const uint32_t GQ;
  typedef __attribute__((address_space(3))) uint32_t LQ;
  __builtin_amdgcn_global_load_lds((GQ*)g, (LQ*)l, 16, 0, 0);
}

__device__ __forceinline__ uint16_t f16_bits(float v) {
  _Float16 h = (_Float16)v;
  return __builtin_bit_cast(uint16_t, h);
}

// v_cvt_pkrtz_f16_f32: pack two f32 -> two f16 in one instruction
__device__ __forceinline__ uint32_t pkrtz(float a, float b) {
  return __builtin_bit_cast(uint32_t, __builtin_amdgcn_cvt_pkrtz(a, b));
}

// XOR-swizzled 64-elem-row tile: 16B unit u of row r lives at physical unit
// u ^ (r&7). Spreads (stride ≡ 0 mod 32 dwords) rows across all 32 banks.
__device__ __forceinline__ int swz(int row, int e) {
  return row * 64 + ((((e >> 3) ^ (row & 7)) << 3) | (e & 7));
}

// ---------------- fused prologue: weight transposes + x convert -------------
// z=0: d0[c][r] = f16(w0[r][c])  (768 x 2304)
// z=1: d1[c][r] = f16(w1[r][c])  (768 x 768), blocks x>=24 idle
// z=2: xc = f16(x), grid-stride over 16B-packs (convert kernel folded in)
__global__ __launch_bounds__(256) void prologue(
    const float* __restrict__ w0, const float* __restrict__ w1,
    uint16_t* __restrict__ d0, uint16_t* __restrict__ d1,
    const float4* __restrict__ xsrc, f16x8* __restrict__ xdst, int n8) {
  const int z = blockIdx.z;
  const int tx = threadIdx.x, ty = threadIdx.y;  // 32 x 8
  if (z == 2) {
    const int nthr = 72 * 24 * 256;
    int i = (blockIdx.y * 72 + blockIdx.x) * 256 + ty * 32 + tx;
    for (; i < n8; i += nthr) {
      const float4 a = xsrc[2 * i], b = xsrc[2 * i + 1];
      f16x8 o;
      o[0] = (_Float16)a.x; o[1] = (_Float16)a.y; o[2] = (_Float16)a.z; o[3] = (_Float16)a.w;
      o[4] = (_Float16)b.x; o[5] = (_Float16)b.y; o[6] = (_Float16)b.z; o[7] = (_Float16)b.w;
      xdst[i] = o;
    }
    return;
  }
  __shared__ uint16_t tile[32][33];
  if (z && blockIdx.x >= 24) return;  // block-uniform early-out
  const float* src = z ? w1 : w0;
  uint16_t* dst = z ? d1 : d0;
  const int C = z ? 768 : 2304;
  const int R = 768;
  const int c0 = blockIdx.x * 32, r0 = blockIdx.y * 32;
#pragma unroll
  for (int i = 0; i < 32; i += 8)
    tile[ty + i][tx] = f16_bits(src[(size_t)(r0 + ty + i) * C + (c0 + tx)]);
  __syncthreads();
#pragma unroll
  for (int i = 0; i < 32; i += 8)
    dst[(size_t)(c0 + ty + i) * R + (r0 + tx)] = tile[tx][ty + i];
}

// ---------------- GEMM: C[m][n] = sum_k A[m][k] * Bt[n][k] + bias[n]
// 3-buffer counted-vmcnt pipeline (T4): STAGE(t+2) issued each iter, DMA
// stays in flight across barriers; vmcnt(4) drains only tile t's loads.
// mode 0: store FP32 to o0 row-major [M][768]
// mode 1: QKV scatter: Q->o0, K->o1 as [B,H,N,64] f16 (Q pre-scaled);
//         V->o2 TRANSPOSED as [B,H,64,N] f16
__global__ __launch_bounds__(256) void gemm_bt(
    const _Float16* __restrict__ A, const _Float16* __restrict__ Bt,
    const float* __restrict__ bias, int K, int mode,
    void* __restrict__ o0, _Float16* __restrict__ o1, _Float16* __restrict__ o2) {
  __shared__ __attribute__((aligned(16))) _Float16 As[3][128 * 32];
  __shared__ __attribute__((aligned(16))) _Float16 Bs[3][128 * 32];
  __shared__ float bias_s[128];
  const int tid = threadIdx.x;
  const int wv = tid >> 6;
  const int lane = tid & 63;
  const int quad = lane >> 4, l16 = lane & 15;
  const int wm = (wv >> 1) * 64, wn = (wv & 1) * 64;
  const int m0 = blockIdx.y * 128, n0 = blockIdx.x * 128;

  if (tid < 128) bias_s[tid] = bias[n0 + tid];

  floatx4 acc[4][4];
#pragma unroll
  for (int i = 0; i < 4; ++i)
#pragma unroll
    for (int j = 0; j < 4; ++j) acc[i][j] = (floatx4){0.f, 0.f, 0.f, 0.f};

  // DMA mapping: wave wv stages A/B tile rows [wv*32, wv*32+32).
  const int gr = lane >> 2, gc = (lane & 3) * 8;
  const _Float16* Ag = A + (size_t)(m0 + wv * 32 + gr) * K + gc;
  const _Float16* Bg = Bt + (size_t)(n0 + wv * 32 + gr) * K + gc;
  const size_t K16 = (size_t)16 * K;

  auto STAGE = [&](int buf, int kt) {
    _Float16* As0 = &As[buf][wv * 1024];
    _Float16* Bs0 = &Bs[buf][wv * 1024];
    gload_lds16(Ag + kt, As0);
    gload_lds16(Ag + kt + K16, As0 + 512);
    gload_lds16(Bg + kt, Bs0);
    gload_lds16(Bg + kt + K16, Bs0 + 512);
  };
  auto COMPUTE = [&](int buf) {
    f16x8 af[4], bfr[4];
#pragma unroll
    for (int i = 0; i < 4; ++i)
      af[i] = *(const f16x8*)&As[buf][(wm + i * 16 + l16) * 32 + quad * 8];
#pragma unroll
    for (int j = 0; j < 4; ++j)
      bfr[j] = *(const f16x8*)&Bs[buf][(wn + j * 16 + l16) * 32 + quad * 8];
    __builtin_amdgcn_s_setprio(1);
#pragma unroll
    for (int i = 0; i < 4; ++i)
#pragma unroll
      for (int j = 0; j < 4; ++j)
        acc[i][j] = __builtin_amdgcn_mfma_f32_16x16x32_f16(af[i], bfr[j], acc[i][j], 0, 0, 0);
    __builtin_amdgcn_s_setprio(0);
  };

  STAGE(0, 0);
  STAGE(1, 32);
  const int nt = K >> 5;
  int b0 = 0, b1 = 1, b2 = 2;
#pragma unroll 1
  for (int t = 0; t < nt - 2; ++t) {
    // tile t landed (its 4 loads are the oldest; 4 newer stay in flight)
    asm volatile("s_waitcnt vmcnt(4)" ::: "memory");
    __builtin_amdgcn_s_barrier();
    STAGE(b2, (t + 2) * 32);
    COMPUTE(b0);
    const int tmp = b0; b0 = b1; b1 = b2; b2 = tmp;
  }
  asm volatile("s_waitcnt vmcnt(4)" ::: "memory");
  __builtin_amdgcn_s_barrier();
  COMPUTE(b0);
  b0 = b1;
  asm volatile("s_waitcnt vmcnt(0)" ::: "memory");
  __builtin_amdgcn_s_barrier();
  COMPUTE(b0);

  if (mode == 0) {
    float* of = (float*)o0;
#pragma unroll
    for (int i = 0; i < 4; ++i)
#pragma unroll
      for (int j = 0; j < 4; ++j) {
        const int col = n0 + wn + j * 16 + l16;
        const float b = bias_s[wn + j * 16 + l16];
        const int mrow = m0 + wm + i * 16 + quad * 4;
#pragma unroll
        for (int r = 0; r < 4; ++r)
          of[(size_t)(mrow + r) * DIMM + col] = acc[i][j][r] + b;
      }
  } else {
    const int sec = n0 / DIMM;  // 0=Q 1=K 2=V
    if (sec < 2) {
      _Float16* dst = (sec == 0) ? (_Float16*)o0 : o1;
      const float sc = (sec == 0) ? 0.18033688011112042f : 1.0f;  // 1/8 * log2(e)
#pragma unroll
      for (int i = 0; i < 4; ++i)
#pragma unroll
        for (int j = 0; j < 4; ++j) {
          const int n = n0 + wn + j * 16 + l16;
          const int c = n - sec * DIMM;
          const int h = c >> 6, d = c & 63;
          const float b = bias_s[wn + j * 16 + l16];
          const int mrow = m0 + wm + i * 16 + quad * 4;
#pragma unroll
          for (int r = 0; r < 4; ++r) {
            const int m = mrow + r;
            const int bb = m >> 12, nr = m & 4095;
            dst[(((size_t)(bb * NHEADS + h)) * NSEQ + nr) * HD + d] =
                (_Float16)((acc[i][j][r] + b) * sc);
          }
        }
    } else {
      // V^T: o2[((bb*NHEADS+h)*HD + d)*NSEQ + nr], nr consecutive over r
#pragma unroll
      for (int i = 0; i < 4; ++i)
#pragma unroll
        for (int j = 0; j < 4; ++j) {
          const int c = n0 + wn + j * 16 + l16 - 2 * DIMM;
          const int h = c >> 6, d = c & 63;
          const float b = bias_s[wn + j * 16 + l16];
          const int mrow = m0 + wm + i * 16 + quad * 4;
          const int bb = mrow >> 12, nr = mrow & 4095;  // same bb for r=0..3
          f16x4 v;
#pragma unroll
          for (int r = 0; r < 4; ++r) v[r] = (_Float16)(acc[i][j][r] + b);
          *(f16x4*)&o2[(((size_t)(bb * NHEADS + h)) * HD + d) * NSEQ + nr] = v;
        }
    }
  }
}

// ---------------- flash attention v8: v7 (P in-register via permlane, zero
// bank conflicts) + row-sum l via MFMA-ones: the 32 VALU adds/wave-region
// move to the 36%-busy MFMA pipe (4 extra MFMA), and lacc[it][r] lands on
// exactly the lane/slot the epilogue needs -> shuffle reduce deleted too. ---
__global__ __launch_bounds__(256, 3) void attn(
    const _Float16* __restrict__ Qg, const _Float16* __restrict__ Kg,
    const _Float16* __restrict__ VTg, _Float16* __restrict__ ctx) {
  __shared__ __attribute__((aligned(16))) _Float16 Pt[128 * 64];  // Q stage
  __shared__ __attribute__((aligned(16))) _Float16 Ks[2][64 * 64];
  __shared__ __attribute__((aligned(16))) _Float16 VTs[2][64 * 64];
  const int tid = threadIdx.x;
  const int wv = tid >> 6, lane = tid & 63;
  const int quad = lane >> 4, l16 = lane & 15;
  // XCD swizzle: 768 blocks; id%8 = XCD -> each XCD owns 3 bh (K/V L2-resident)
  const int bi = blockIdx.x;
  const int xcd = bi & 7, j = bi >> 3;
  const int bh = xcd * 3 + (j >> 5);
  const int q0 = (j & 31) * 128;
  const int bb = bh / NHEADS, h = bh - bb * NHEADS;
  const _Float16* Qp = Qg + (size_t)bh * NSEQ * HD;
  const _Float16* Kp = Kg + (size_t)bh * NSEQ * HD;
  const _Float16* VTp = VTg + (size_t)bh * HD * NSEQ;

  const int krow = tid >> 3;
  // DMA lane->global-unit permute implements the XOR swizzle
  const int kcol = (((tid & 7) ^ ((tid >> 3) & 7)) * 8);

  // preamble: DMA Q tile [128][64] into Pt area + KV tile 0 into buf0
#pragma unroll
  for (int i = 0; i < 4; ++i)
    gload_lds16(Qp + (size_t)(q0 + i * 32 + krow) * HD + kcol, &Pt[(i * 256 + wv * 64) * 8]);
#pragma unroll
  for (int i = 0; i < 2; ++i) {
    gload_lds16(Kp + (size_t)(i * 32 + krow) * HD + kcol, &Ks[0][(i * 256 + wv * 64) * 8]);
    gload_lds16(VTp + (size_t)(i * 32 + krow) * NSEQ + kcol, &VTs[0][(i * 256 + wv * 64) * 8]);
  }
  __syncthreads();  // drains DMA: Q + buf0 visible

  f16x8 aq[2][2];
#pragma unroll
  for (int it = 0; it < 2; ++it)
#pragma unroll
    for (int ks = 0; ks < 2; ++ks)
      aq[it][ks] = *(const f16x8*)&Pt[swz(wv * 32 + it * 16 + l16, ks * 32 + quad * 8)];

  // issue DMA tile1 -> buf1 (drained at the first loop barrier)
#pragma unroll
  for (int i = 0; i < 2; ++i) {
    gload_lds16(Kp + (size_t)(64 + i * 32 + krow) * HD + kcol, &Ks[1][(i * 256 + wv * 64) * 8]);
    gload_lds16(VTp + (size_t)(i * 32 + krow) * NSEQ + 64 + kcol, &VTs[1][(i * 256 + wv * 64) * 8]);
  }

  f16x8 ones;
#pragma unroll
  for (int e = 0; e < 8; ++e) ones[e] = (_Float16)1.0f;

  floatx4 o[2][4];
  floatx4 lacc[2];
#pragma unroll
  for (int it = 0; it < 2; ++it) {
    lacc[it] = (floatx4){0.f, 0.f, 0.f, 0.f};
#pragma unroll
    for (int jn = 0; jn < 4; ++jn) o[it][jn] = (floatx4){0.f, 0.f, 0.f, 0.f};
  }

  f16x8 vr[2][4];   // V(t) fragments carried across the barrier
  f16x8 ap[2][2];   // P(t) A-fragments, built in-register by SMAX

  // S^T = K . Q^T  (exp2-domain: Q pre-scaled by 0.125*log2e)
  auto QKT = [&](const _Float16* bK, floatx4 (&s)[2][4]) {
#pragma unroll
    for (int ks = 0; ks < 2; ++ks) {
#pragma unroll
      for (int im = 0; im < 4; ++im) {
        const f16x8 bk = *(const f16x8*)&bK[swz(im * 16 + l16, ks * 32 + quad * 8)];
        s[0][im] = __builtin_amdgcn_mfma_f32_16x16x32_f16(bk, aq[0][ks], s[0][im], 0, 0, 0);
        s[1][im] = __builtin_amdgcn_mfma_f32_16x16x32_f16(bk, aq[1][ks], s[1][im], 0, 0, 0);
      }
    }
  };
  auto LDVR = [&](const _Float16* bV) {
#pragma unroll
    for (int kk = 0; kk < 2; ++kk)
#pragma unroll
      for (int jn = 0; jn < 4; ++jn)
        vr[kk][jn] = *(const f16x8*)&bV[swz(jn * 16 + l16, kk * 32 + quad * 8)];
  };
  // p = exp2(s); pkrtz pack; permlane quad-redistribute C->A layout in-reg.
  // (row-sum l is NOT accumulated here; PV's MFMA-ones handles it.)
  auto SMAX = [&](floatx4 (&s)[2][4]) {
#pragma unroll
    for (int it = 0; it < 2; ++it) {
      uint32_t w[4][2];
#pragma unroll
      for (int im = 0; im < 4; ++im) {
        float p0 = __builtin_amdgcn_exp2f(s[it][im][0]);
        float p1 = __builtin_amdgcn_exp2f(s[it][im][1]);
        float p2 = __builtin_amdgcn_exp2f(s[it][im][2]);
        float p3 = __builtin_amdgcn_exp2f(s[it][im][3]);
        w[im][0] = pkrtz(p0, p1);
        w[im][1] = pkrtz(p2, p3);
      }
#pragma unroll
      for (int kk = 0; kk < 2; ++kk) {
        uint32_t a = w[2 * kk][0], c = w[2 * kk + 1][0];
        uint32_t b = w[2 * kk][1], d = w[2 * kk + 1][1];
        asm("v_permlane32_swap_b32 %0, %1" : "+v"(a), "+v"(c));
        asm("v_permlane16_swap_b32 %0, %1" : "+v"(a), "+v"(c));
        asm("v_permlane32_swap_b32 %0, %1" : "+v"(b), "+v"(d));
        asm("v_permlane16_swap_b32 %0, %1" : "+v"(b), "+v"(d));
        const u32x4 pk = {a, b, c, d};
        ap[kk][it] = __builtin_bit_cast(f16x8, pk);
      }
    }
  };
  auto PV = [&]() {
#pragma unroll
    for (int kk = 0; kk < 2; ++kk) {
      lacc[0] = __builtin_amdgcn_mfma_f32_16x16x32_f16(ap[kk][0], ones, lacc[0], 0, 0, 0);
      lacc[1] = __builtin_amdgcn_mfma_f32_16x16x32_f16(ap[kk][1], ones, lacc[1], 0, 0, 0);
#pragma unroll
      for (int jn = 0; jn < 4; ++jn) {
        o[0][jn] = __builtin_amdgcn_mfma_f32_16x16x32_f16(ap[kk][0], vr[kk][jn], o[0][jn], 0, 0, 0);
        o[1][jn] = __builtin_amdgcn_mfma_f32_16x16x32_f16(ap[kk][1], vr[kk][jn], o[1][jn], 0, 0, 0);
      }
    }
  };

  // region 0 (no PV): QK^T(0), stash V(0) in regs, softmax(0) -> ap
  {
    floatx4 s[2][4];
#pragma unroll
    for (int it = 0; it < 2; ++it)
#pragma unroll
      for (int im = 0; im < 4; ++im) s[it][im] = (floatx4){0.f, 0.f, 0.f, 0.f};
    __builtin_amdgcn_s_setprio(1);
    QKT(Ks[0], s);
    __builtin_amdgcn_s_setprio(0);
    LDVR(VTs[0]);
    SMAX(s);
  }

  // region t (t>=1): barrier; DMA(t+1); QK^T(t) + PV(t-1) MFMA cluster;
  // reload vr = V(t); softmax(t) -> ap (in-register) tail.
  auto REGION = [&](const _Float16* bK, const _Float16* bV,
                    _Float16* wK, _Float16* wV, int kvn, bool dodma) {
    __syncthreads();  // readers of wK/wV done; DMA(t) drained (vmcnt0)
    if (dodma) {
#pragma unroll
      for (int i = 0; i < 2; ++i) {
        gload_lds16(Kp + (size_t)(kvn + i * 32 + krow) * HD + kcol, &wK[(i * 256 + wv * 64) * 8]);
        gload_lds16(VTp + (size_t)(i * 32 + krow) * NSEQ + kvn + kcol, &wV[(i * 256 + wv * 64) * 8]);
      }
    }
    floatx4 s[2][4];
#pragma unroll
    for (int it = 0; it < 2; ++it)
#pragma unroll
      for (int im = 0; im < 4; ++im) s[it][im] = (floatx4){0.f, 0.f, 0.f, 0.f};
    __builtin_amdgcn_s_setprio(1);
    QKT(bK, s);
    PV();      // consumes ap,vr = region t-1; accumulates o and lacc
    __builtin_amdgcn_s_setprio(0);
    LDVR(bV);  // vr = V(t) for next region's PV
    SMAX(s);   // ap = P(t) in-register
  };

#pragma unroll 1
  for (int p = 0; p < 31; ++p) {
    const int t0 = 2 * p + 1;
    REGION(Ks[1], VTs[1], Ks[0], VTs[0], (t0 + 1) * 64, true);
    REGION(Ks[0], VTs[0], Ks[1], VTs[1], (t0 + 2) * 64, true);
  }
  REGION(Ks[1], VTs[1], Ks[0], VTs[0], 0, false);  // t=63, no DMA
  PV();  // final PV(63): all in-register

  // epilogue: l[q] sits in lacc[it][r] on exactly this lane -- no shuffles
#pragma unroll
  for (int it = 0; it < 2; ++it)
#pragma unroll
    for (int r = 0; r < 4; ++r) {
      const int q = q0 + wv * 32 + it * 16 + quad * 4 + r;
      const float inv = 1.0f / lacc[it][r];
      _Float16* dst = ctx + (size_t)(bb * NSEQ + q) * DIMM + h * HD;
#pragma unroll
      for (int jn = 0; jn < 4; ++jn)
        dst[jn * 16 + l16] = (_Float16)(o[it][jn][r] * inv);
    }
}

extern "C" void kernel_launch(void* const* d_in, const int* in_sizes, int n_in,
                              void* d_out, int out_size, void* d_ws, size_t ws_size,
                              hipStream_t stream) {
  char* ws = (char*)d_ws;
  _Float16* xc = (_Float16*)ws;      ws += (size_t)8192 * 768 * 2;
  _Float16* wqkvT = (_Float16*)ws;   ws += (size_t)2304 * 768 * 2;
  _Float16* wprojT = (_Float16*)ws;  ws += (size_t)768 * 768 * 2;
  const size_t qkv_elems = (size_t)2 * NHEADS * NSEQ * HD;
  _Float16* Qb = (_Float16*)ws;      ws += qkv_elems * 2;
  _Float16* Kb = (_Float16*)ws;      ws += qkv_elems * 2;
  _Float16* VTb = (_Float16*)ws;     ws += qkv_elems * 2;
  _Float16* ctx = xc;  // x dead after QKV GEMM; reuse as attention output

  const dim3 tb(32, 8, 1);
  const dim3 b256(256, 1, 1);
  hipLaunchKernelGGL(prologue, dim3(72, 24, 3), tb, 0, stream,
                     (const float*)d_in[1], (const float*)d_in[3],
                     (uint16_t*)wqkvT, (uint16_t*)wprojT,
                     (const float4*)d_in[0], (f16x8*)xc, 8192 * 768 / 8);
  hipLaunchKernelGGL(gemm_bt, dim3(18, 64, 1), b256, 0, stream,
                     xc, wqkvT, (const float*)d_in[2], 768, 1, (void*)Qb, Kb, VTb);
  hipLaunchKernelGGL(attn, dim3(768, 1, 1), b256, 0, stream, Qb, Kb, VTb, ctx);
  hipLaunchKernelGGL(gemm_bt, dim3(6, 64, 1), b256, 0, stream,
                     ctx, wprojT, (const float*)d_in[4], 768, 0, d_out,
                     (_Float16*)nullptr, (_Float16*)nullptr);
}

// Round 9
// 264.833 us; speedup vs baseline: 1.3717x; 1.0040x over previous
//
#include <hip/hip_runtime.h>
#include <hip/hip_bf16.h>
#include <stdint.h>

typedef _Float16 f16x8 __attribute__((ext_vector_type(8)));
typedef _Float16 f16x4 __attribute__((ext_vector_type(4)));
typedef uint32_t u32x2 __attribute__((ext_vector_type(2)));
typedef uint32_t u32x4 __attribute__((ext_vector_type(4)));
typedef float floatx4 __attribute__((ext_vector_type(4)));

#define NSEQ 4096
#define DIMM 768
#define NHEADS 12
#define HD 64

__device__ __forceinline__ void gload_lds16(const void* g, void* l) {
  typedef __attribute__((address_space(1))) const uint32_t GQ;
  typedef __attribute__((address_space(3))) uint32_t LQ;
  __builtin_amdgcn_global_load_lds((GQ*)g, (LQ*)l, 16, 0, 0);
}

__device__ __forceinline__ uint16_t f16_bits(float v) {
  _Float16 h = (_Float16)v;
  return __builtin_bit_cast(uint16_t, h);
}

// v_cvt_pkrtz_f16_f32: pack two f32 -> two f16 in one instruction
__device__ __forceinline__ uint32_t pkrtz(float a, float b) {
  return __builtin_bit_cast(uint32_t, __builtin_amdgcn_cvt_pkrtz(a, b));
}

// XOR-swizzled 64-elem-row tile: 16B unit u of row r lives at physical unit
// u ^ (r&7). Spreads (stride ≡ 0 mod 32 dwords) rows across all 32 banks.
__device__ __forceinline__ int swz(int row, int e) {
  return row * 64 + ((((e >> 3) ^ (row & 7)) << 3) | (e & 7));
}

// ---------------- fused prologue: weight transposes + x convert -------------
// z=0: d0[c][r] = f16(w0[r][c])  (768 x 2304)
// z=1: d1[c][r] = f16(w1[r][c])  (768 x 768), blocks x>=24 idle
// z=2: xc = f16(x), grid-stride over 16B-packs (convert kernel folded in)
__global__ __launch_bounds__(256) void prologue(
    const float* __restrict__ w0, const float* __restrict__ w1,
    uint16_t* __restrict__ d0, uint16_t* __restrict__ d1,
    const float4* __restrict__ xsrc, f16x8* __restrict__ xdst, int n8) {
  const int z = blockIdx.z;
  const int tx = threadIdx.x, ty = threadIdx.y;  // 32 x 8
  if (z == 2) {
    const int nthr = 72 * 24 * 256;
    int i = (blockIdx.y * 72 + blockIdx.x) * 256 + ty * 32 + tx;
    for (; i < n8; i += nthr) {
      const float4 a = xsrc[2 * i], b = xsrc[2 * i + 1];
      f16x8 o;
      o[0] = (_Float16)a.x; o[1] = (_Float16)a.y; o[2] = (_Float16)a.z; o[3] = (_Float16)a.w;
      o[4] = (_Float16)b.x; o[5] = (_Float16)b.y; o[6] = (_Float16)b.z; o[7] = (_Float16)b.w;
      xdst[i] = o;
    }
    return;
  }
  __shared__ uint16_t tile[32][33];
  if (z && blockIdx.x >= 24) return;  // block-uniform early-out
  const float* src = z ? w1 : w0;
  uint16_t* dst = z ? d1 : d0;
  const int C = z ? 768 : 2304;
  const int R = 768;
  const int c0 = blockIdx.x * 32, r0 = blockIdx.y * 32;
#pragma unroll
  for (int i = 0; i < 32; i += 8)
    tile[ty + i][tx] = f16_bits(src[(size_t)(r0 + ty + i) * C + (c0 + tx)]);
  __syncthreads();
#pragma unroll
  for (int i = 0; i < 32; i += 8)
    dst[(size_t)(c0 + ty + i) * R + (r0 + tx)] = tile[tx][ty + i];
}

// ---------------- GEMM: C[m][n] = sum_k A[m][k] * Bt[n][k] + bias[n]
// 3-buffer counted-vmcnt pipeline (T4): STAGE(t+2) issued each iter, DMA
// stays in flight across barriers; vmcnt(4) drains only tile t's loads.
// mode 0: store FP32 to o0 row-major [M][768]
// mode 1: QKV scatter: Q->o0, K->o1 as [B,H,N,64] f16 (Q pre-scaled);
//         V->o2 TRANSPOSED as [B,H,64,N] f16
__global__ __launch_bounds__(256) void gemm_bt(
    const _Float16* __restrict__ A, const _Float16* __restrict__ Bt,
    const float* __restrict__ bias, int K, int mode,
    void* __restrict__ o0, _Float16* __restrict__ o1, _Float16* __restrict__ o2) {
  __shared__ __attribute__((aligned(16))) _Float16 As[3][128 * 32];
  __shared__ __attribute__((aligned(16))) _Float16 Bs[3][128 * 32];
  __shared__ float bias_s[128];
  const int tid = threadIdx.x;
  const int wv = tid >> 6;
  const int lane = tid & 63;
  const int quad = lane >> 4, l16 = lane & 15;
  const int wm = (wv >> 1) * 64, wn = (wv & 1) * 64;
  const int m0 = blockIdx.y * 128, n0 = blockIdx.x * 128;

  if (tid < 128) bias_s[tid] = bias[n0 + tid];

  floatx4 acc[4][4];
#pragma unroll
  for (int i = 0; i < 4; ++i)
#pragma unroll
    for (int j = 0; j < 4; ++j) acc[i][j] = (floatx4){0.f, 0.f, 0.f, 0.f};

  // DMA mapping: wave wv stages A/B tile rows [wv*32, wv*32+32).
  const int gr = lane >> 2, gc = (lane & 3) * 8;
  const _Float16* Ag = A + (size_t)(m0 + wv * 32 + gr) * K + gc;
  const _Float16* Bg = Bt + (size_t)(n0 + wv * 32 + gr) * K + gc;
  const size_t K16 = (size_t)16 * K;

  auto STAGE = [&](int buf, int kt) {
    _Float16* As0 = &As[buf][wv * 1024];
    _Float16* Bs0 = &Bs[buf][wv * 1024];
    gload_lds16(Ag + kt, As0);
    gload_lds16(Ag + kt + K16, As0 + 512);
    gload_lds16(Bg + kt, Bs0);
    gload_lds16(Bg + kt + K16, Bs0 + 512);
  };
  auto COMPUTE = [&](int buf) {
    f16x8 af[4], bfr[4];
#pragma unroll
    for (int i = 0; i < 4; ++i)
      af[i] = *(const f16x8*)&As[buf][(wm + i * 16 + l16) * 32 + quad * 8];
#pragma unroll
    for (int j = 0; j < 4; ++j)
      bfr[j] = *(const f16x8*)&Bs[buf][(wn + j * 16 + l16) * 32 + quad * 8];
    __builtin_amdgcn_s_setprio(1);
#pragma unroll
    for (int i = 0; i < 4; ++i)
#pragma unroll
      for (int j = 0; j < 4; ++j)
        acc[i][j] = __builtin_amdgcn_mfma_f32_16x16x32_f16(af[i], bfr[j], acc[i][j], 0, 0, 0);
    __builtin_amdgcn_s_setprio(0);
  };

  STAGE(0, 0);
  STAGE(1, 32);
  const int nt = K >> 5;
  int b0 = 0, b1 = 1, b2 = 2;
#pragma unroll 1
  for (int t = 0; t < nt - 2; ++t) {
    // tile t landed (its 4 loads are the oldest; 4 newer stay in flight)
    asm volatile("s_waitcnt vmcnt(4)" ::: "memory");
    __builtin_amdgcn_s_barrier();
    STAGE(b2, (t + 2) * 32);
    COMPUTE(b0);
    const int tmp = b0; b0 = b1; b1 = b2; b2 = tmp;
  }
  asm volatile("s_waitcnt vmcnt(4)" ::: "memory");
  __builtin_amdgcn_s_barrier();
  COMPUTE(b0);
  b0 = b1;
  asm volatile("s_waitcnt vmcnt(0)" ::: "memory");
  __builtin_amdgcn_s_barrier();
  COMPUTE(b0);

  if (mode == 0) {
    float* of = (float*)o0;
#pragma unroll
    for (int i = 0; i < 4; ++i)
#pragma unroll
      for (int j = 0; j < 4; ++j) {
        const int col = n0 + wn + j * 16 + l16;
        const float b = bias_s[wn + j * 16 + l16];
        const int mrow = m0 + wm + i * 16 + quad * 4;
#pragma unroll
        for (int r = 0; r < 4; ++r)
          of[(size_t)(mrow + r) * DIMM + col] = acc[i][j][r] + b;
      }
  } else {
    const int sec = n0 / DIMM;  // 0=Q 1=K 2=V
    if (sec < 2) {
      _Float16* dst = (sec == 0) ? (_Float16*)o0 : o1;
      const float sc = (sec == 0) ? 0.18033688011112042f : 1.0f;  // 1/8 * log2(e)
#pragma unroll
      for (int i = 0; i < 4; ++i)
#pragma unroll
        for (int j = 0; j < 4; ++j) {
          const int n = n0 + wn + j * 16 + l16;
          const int c = n - sec * DIMM;
          const int h = c >> 6, d = c & 63;
          const float b = bias_s[wn + j * 16 + l16];
          const int mrow = m0 + wm + i * 16 + quad * 4;
#pragma unroll
          for (int r = 0; r < 4; ++r) {
            const int m = mrow + r;
            const int bb = m >> 12, nr = m & 4095;
            dst[(((size_t)(bb * NHEADS + h)) * NSEQ + nr) * HD + d] =
                (_Float16)((acc[i][j][r] + b) * sc);
          }
        }
    } else {
      // V^T: o2[((bb*NHEADS+h)*HD + d)*NSEQ + nr], nr consecutive over r
#pragma unroll
      for (int i = 0; i < 4; ++i)
#pragma unroll
        for (int j = 0; j < 4; ++j) {
          const int c = n0 + wn + j * 16 + l16 - 2 * DIMM;
          const int h = c >> 6, d = c & 63;
          const float b = bias_s[wn + j * 16 + l16];
          const int mrow = m0 + wm + i * 16 + quad * 4;
          const int bb = mrow >> 12, nr = mrow & 4095;  // same bb for r=0..3
          f16x4 v;
#pragma unroll
          for (int r = 0; r < 4; ++r) v[r] = (_Float16)(acc[i][j][r] + b);
          *(f16x4*)&o2[(((size_t)(bb * NHEADS + h)) * HD + d) * NSEQ + nr] = v;
        }
    }
  }
}

// ---------------- flash attention v9: v8 (P in-register, MFMA-ones l) +
// COUNTED-VMCNT REGION PIPELINE (T4): 3-deep K/V buffers; per-region entry
// is {lgkmcnt(0); vmcnt(4); s_barrier} -- DMA group t+1 stays in flight
// across the barrier (never drain to 0 in the loop). lgkmcnt(0) before the
// barrier closes the cross-wave LDS writer-after-reader race architecturally.
// Q stages through the Ks buffers (dedicated Pt buffer deleted). -------------
__global__ __launch_bounds__(256, 3) void attn(
    const _Float16* __restrict__ Qg, const _Float16* __restrict__ Kg,
    const _Float16* __restrict__ VTg, _Float16* __restrict__ ctx) {
  __shared__ __attribute__((aligned(16))) _Float16 Ks[3][64 * 64];
  __shared__ __attribute__((aligned(16))) _Float16 VTs[3][64 * 64];
  const int tid = threadIdx.x;
  const int wv = tid >> 6, lane = tid & 63;
  const int quad = lane >> 4, l16 = lane & 15;
  // XCD swizzle: 768 blocks; id%8 = XCD -> each XCD owns 3 bh (K/V L2-resident)
  const int bi = blockIdx.x;
  const int xcd = bi & 7, j = bi >> 3;
  const int bh = xcd * 3 + (j >> 5);
  const int q0 = (j & 31) * 128;
  const int bb = bh / NHEADS, h = bh - bb * NHEADS;
  const _Float16* Qp = Qg + (size_t)bh * NSEQ * HD;
  const _Float16* Kp = Kg + (size_t)bh * NSEQ * HD;
  const _Float16* VTp = VTg + (size_t)bh * HD * NSEQ;

  const int krow = tid >> 3;
  // DMA lane->global-unit permute implements the XOR swizzle
  const int kcol = (((tid & 7) ^ ((tid >> 3) & 7)) * 8);

  // preamble: stage Q tile [128][64] through Ks[0..1] (16KB), read aq, then
  // repurpose the buffers for the K/V pipeline.
  _Float16* qstage = &Ks[0][0];
#pragma unroll
  for (int i = 0; i < 4; ++i)
    gload_lds16(Qp + (size_t)(q0 + i * 32 + krow) * HD + kcol, &qstage[(i * 256 + wv * 64) * 8]);
  __syncthreads();  // drains Q DMA

  f16x8 aq[2][2];
#pragma unroll
  for (int it = 0; it < 2; ++it)
#pragma unroll
    for (int ks = 0; ks < 2; ++ks)
      aq[it][ks] = *(const f16x8*)&qstage[swz(wv * 32 + it * 16 + l16, ks * 32 + quad * 8)];
  asm volatile("s_waitcnt lgkmcnt(0)" ::: "memory");
  __builtin_amdgcn_s_barrier();  // all waves done reading Q from Ks

  auto GDMA = [&](int kvn, _Float16* wK, _Float16* wV) {
#pragma unroll
    for (int i = 0; i < 2; ++i) {
      gload_lds16(Kp + (size_t)(kvn + i * 32 + krow) * HD + kcol, &wK[(i * 256 + wv * 64) * 8]);
      gload_lds16(VTp + (size_t)(i * 32 + krow) * NSEQ + kvn + kcol, &wV[(i * 256 + wv * 64) * 8]);
    }
  };

  // fill: G(0)->buf0, G(1)->buf1 (8 loads outstanding)
  GDMA(0, Ks[0], VTs[0]);
  GDMA(64, Ks[1], VTs[1]);

  const floatx4 zero4 = (floatx4){0.f, 0.f, 0.f, 0.f};
  f16x8 ones;
#pragma unroll
  for (int e = 0; e < 8; ++e) ones[e] = (_Float16)1.0f;

  floatx4 o[2][4];
  floatx4 lacc[2];
#pragma unroll
  for (int it = 0; it < 2; ++it) {
    lacc[it] = zero4;
#pragma unroll
    for (int jn = 0; jn < 4; ++jn) o[it][jn] = zero4;
  }

  f16x8 vr[2][4];   // V(t) fragments carried across the barrier
  f16x8 ap[2][2];   // P(t) A-fragments, built in-register by SMAX

  // S^T = K . Q^T  (exp2-domain: Q pre-scaled by 0.125*log2e).
  // First K-slice uses zero4 as C (no per-region accumulator zero-init).
  auto QKT = [&](const _Float16* bK, floatx4 (&s)[2][4]) {
#pragma unroll
    for (int im = 0; im < 4; ++im) {
      const f16x8 bk = *(const f16x8*)&bK[swz(im * 16 + l16, quad * 8)];
      s[0][im] = __builtin_amdgcn_mfma_f32_16x16x32_f16(bk, aq[0][0], zero4, 0, 0, 0);
      s[1][im] = __builtin_amdgcn_mfma_f32_16x16x32_f16(bk, aq[1][0], zero4, 0, 0, 0);
    }
#pragma unroll
    for (int im = 0; im < 4; ++im) {
      const f16x8 bk = *(const f16x8*)&bK[swz(im * 16 + l16, 32 + quad * 8)];
      s[0][im] = __builtin_amdgcn_mfma_f32_16x16x32_f16(bk, aq[0][1], s[0][im], 0, 0, 0);
      s[1][im] = __builtin_amdgcn_mfma_f32_16x16x32_f16(bk, aq[1][1], s[1][im], 0, 0, 0);
    }
  };
  auto LDVR = [&](const _Float16* bV) {
#pragma unroll
    for (int kk = 0; kk < 2; ++kk)
#pragma unroll
      for (int jn = 0; jn < 4; ++jn)
        vr[kk][jn] = *(const f16x8*)&bV[swz(jn * 16 + l16, kk * 32 + quad * 8)];
  };
  // p = exp2(s); pkrtz pack; permlane quad-redistribute C->A layout in-reg.
  auto SMAX = [&](floatx4 (&s)[2][4]) {
#pragma unroll
    for (int it = 0; it < 2; ++it) {
      uint32_t w[4][2];
#pragma unroll
      for (int im = 0; im < 4; ++im) {
        float p0 = __builtin_amdgcn_exp2f(s[it][im][0]);
        float p1 = __builtin_amdgcn_exp2f(s[it][im][1]);
        float p2 = __builtin_amdgcn_exp2f(s[it][im][2]);
        float p3 = __builtin_amdgcn_exp2f(s[it][im][3]);
        w[im][0] = pkrtz(p0, p1);
        w[im][1] = pkrtz(p2, p3);
      }
#pragma unroll
      for (int kk = 0; kk < 2; ++kk) {
        uint32_t a = w[2 * kk][0], c = w[2 * kk + 1][0];
        uint32_t b = w[2 * kk][1], d = w[2 * kk + 1][1];
        asm("v_permlane32_swap_b32 %0, %1" : "+v"(a), "+v"(c));
        asm("v_permlane16_swap_b32 %0, %1" : "+v"(a), "+v"(c));
        asm("v_permlane32_swap_b32 %0, %1" : "+v"(b), "+v"(d));
        asm("v_permlane16_swap_b32 %0, %1" : "+v"(b), "+v"(d));
        const u32x4 pk = {a, b, c, d};
        ap[kk][it] = __builtin_bit_cast(f16x8, pk);
      }
    }
  };
  auto PV = [&]() {
#pragma unroll
    for (int kk = 0; kk < 2; ++kk) {
      lacc[0] = __builtin_amdgcn_mfma_f32_16x16x32_f16(ap[kk][0], ones, lacc[0], 0, 0, 0);
      lacc[1] = __builtin_amdgcn_mfma_f32_16x16x32_f16(ap[kk][1], ones, lacc[1], 0, 0, 0);
#pragma unroll
      for (int jn = 0; jn < 4; ++jn) {
        o[0][jn] = __builtin_amdgcn_mfma_f32_16x16x32_f16(ap[kk][0], vr[kk][jn], o[0][jn], 0, 0, 0);
        o[1][jn] = __builtin_amdgcn_mfma_f32_16x16x32_f16(ap[kk][1], vr[kk][jn], o[1][jn], 0, 0, 0);
      }
    }
  };

  // region 0 (no PV): vmcnt(4) -> G(0) landed; issue G(2); QK^T(0); softmax
  {
    asm volatile("s_waitcnt vmcnt(4)" ::: "memory");
    __builtin_amdgcn_s_barrier();
    GDMA(2 * 64, Ks[2], VTs[2]);
    floatx4 s[2][4];
    __builtin_amdgcn_s_setprio(1);
    QKT(Ks[0], s);
    __builtin_amdgcn_s_setprio(0);
    LDVR(VTs[0]);
    SMAX(s);
  }

  // region r: {lgkmcnt(0); vmcnt(4); s_barrier}; issue G(r+2); QK^T(r)+PV(r-1)
  // cluster; vr = V(r); softmax(r) tail. G(r+1) never drained here.
  auto REGION = [&](const _Float16* bK, const _Float16* bV,
                    _Float16* wK, _Float16* wV, int kvn) {
    asm volatile("s_waitcnt lgkmcnt(0)" ::: "memory");
    asm volatile("s_waitcnt vmcnt(4)" ::: "memory");
    __builtin_amdgcn_s_barrier();
    GDMA(kvn, wK, wV);
    floatx4 s[2][4];
    __builtin_amdgcn_s_setprio(1);
    QKT(bK, s);
    PV();      // consumes ap,vr = region r-1; accumulates o and lacc
    __builtin_amdgcn_s_setprio(0);
    LDVR(bV);  // vr = V(r) for next region's PV
    SMAX(s);   // ap = P(r) in-register
  };

#pragma unroll 1
  for (int p = 0; p < 21; ++p) {
    const int r = 3 * p + 1;  // regions r, r+1, r+2  (1..63)
    REGION(Ks[1], VTs[1], Ks[0], VTs[0], ((r + 2) & 63) * 64);
    REGION(Ks[2], VTs[2], Ks[1], VTs[1], ((r + 3) & 63) * 64);
    REGION(Ks[0], VTs[0], Ks[2], VTs[2], ((r + 4) & 63) * 64);
  }
  PV();  // final PV(63): all in-register

  // epilogue: l[q] sits in lacc[it][r] on exactly this lane -- no shuffles
#pragma unroll
  for (int it = 0; it < 2; ++it)
#pragma unroll
    for (int r = 0; r < 4; ++r) {
      const int q = q0 + wv * 32 + it * 16 + quad * 4 + r;
      const float inv = 1.0f / lacc[it][r];
      _Float16* dst = ctx + (size_t)(bb * NSEQ + q) * DIMM + h * HD;
#pragma unroll
      for (int jn = 0; jn < 4; ++jn)
        dst[jn * 16 + l16] = (_Float16)(o[it][jn][r] * inv);
    }
}

extern "C" void kernel_launch(void* const* d_in, const int* in_sizes, int n_in,
                              void* d_out, int out_size, void* d_ws, size_t ws_size,
                              hipStream_t stream) {
  char* ws = (char*)d_ws;
  _Float16* xc = (_Float16*)ws;      ws += (size_t)8192 * 768 * 2;
  _Float16* wqkvT = (_Float16*)ws;   ws += (size_t)2304 * 768 * 2;
  _Float16* wprojT = (_Float16*)ws;  ws += (size_t)768 * 768 * 2;
  const size_t qkv_elems = (size_t)2 * NHEADS * NSEQ * HD;
  _Float16* Qb = (_Float16*)ws;      ws += qkv_elems * 2;
  _Float16* Kb = (_Float16*)ws;      ws += qkv_elems * 2;
  _Float16* VTb = (_Float16*)ws;     ws += qkv_elems * 2;
  _Float16* ctx = xc;  // x dead after QKV GEMM; reuse as attention output

  const dim3 tb(32, 8, 1);
  const dim3 b256(256, 1, 1);
  hipLaunchKernelGGL(prologue, dim3(72, 24, 3), tb, 0, stream,
                     (const float*)d_in[1], (const float*)d_in[3],
                     (uint16_t*)wqkvT, (uint16_t*)wprojT,
                     (const float4*)d_in[0], (f16x8*)xc, 8192 * 768 / 8);
  hipLaunchKernelGGL(gemm_bt, dim3(18, 64, 1), b256, 0, stream,
                     xc, wqkvT, (const float*)d_in[2], 768, 1, (void*)Qb, Kb, VTb);
  hipLaunchKernelGGL(attn, dim3(768, 1, 1), b256, 0, stream, Qb, Kb, VTb, ctx);
  hipLaunchKernelGGL(gemm_bt, dim3(6, 64, 1), b256, 0, stream,
                     ctx, wprojT, (const float*)d_in[4], 768, 0, d_out,
                     (_Float16*)nullptr, (_Float16*)nullptr);
}

// Round 10
// 258.927 us; speedup vs baseline: 1.4030x; 1.0228x over previous
//
#include <hip/hip_runtime.h>
#include <hip/hip_bf16.h>
#include <stdint.h>

typedef _Float16 f16x8 __attribute__((ext_vector_type(8)));
typedef _Float16 f16x4 __attribute__((ext_vector_type(4)));
typedef uint32_t u32x2 __attribute__((ext_vector_type(2)));
typedef uint32_t u32x4 __attribute__((ext_vector_type(4)));
typedef float floatx4 __attribute__((ext_vector_type(4)));

#define NSEQ 4096
#define DIMM 768
#define NHEADS 12
#define HD 64

__device__ __forceinline__ void gload_lds16(const void* g, void* l) {
  typedef __attribute__((address_space(1))) const uint32_t GQ;
  typedef __attribute__((address_space(3))) uint32_t LQ;
  __builtin_amdgcn_global_load_lds((GQ*)g, (LQ*)l, 16, 0, 0);
}

__device__ __forceinline__ uint16_t f16_bits(float v) {
  _Float16 h = (_Float16)v;
  return __builtin_bit_cast(uint16_t, h);
}

// v_cvt_pkrtz_f16_f32: pack two f32 -> two f16 in one instruction
__device__ __forceinline__ uint32_t pkrtz(float a, float b) {
  return __builtin_bit_cast(uint32_t, __builtin_amdgcn_cvt_pkrtz(a, b));
}

// XOR-swizzled 64-elem-row tile: 16B unit u of row r lives at physical unit
// u ^ (r&7). Spreads (stride ≡ 0 mod 32 dwords) rows across all 32 banks.
__device__ __forceinline__ int swz(int row, int e) {
  return row * 64 + ((((e >> 3) ^ (row & 7)) << 3) | (e & 7));
}

// ---------------- fused prologue: weight transposes + x convert -------------
// z=0: d0[c][r] = f16(w0[r][c])  (768 x 2304)
// z=1: d1[c][r] = f16(w1[r][c])  (768 x 768), blocks x>=24 idle
// z=2: xc = f16(x), grid-stride over 16B-packs (convert kernel folded in)
__global__ __launch_bounds__(256) void prologue(
    const float* __restrict__ w0, const float* __restrict__ w1,
    uint16_t* __restrict__ d0, uint16_t* __restrict__ d1,
    const float4* __restrict__ xsrc, f16x8* __restrict__ xdst, int n8) {
  const int z = blockIdx.z;
  const int tx = threadIdx.x, ty = threadIdx.y;  // 32 x 8
  if (z == 2) {
    const int nthr = 72 * 24 * 256;
    int i = (blockIdx.y * 72 + blockIdx.x) * 256 + ty * 32 + tx;
    for (; i < n8; i += nthr) {
      const float4 a = xsrc[2 * i], b = xsrc[2 * i + 1];
      f16x8 o;
      o[0] = (_Float16)a.x; o[1] = (_Float16)a.y; o[2] = (_Float16)a.z; o[3] = (_Float16)a.w;
      o[4] = (_Float16)b.x; o[5] = (_Float16)b.y; o[6] = (_Float16)b.z; o[7] = (_Float16)b.w;
      xdst[i] = o;
    }
    return;
  }
  __shared__ uint16_t tile[32][33];
  if (z && blockIdx.x >= 24) return;  // block-uniform early-out
  const float* src = z ? w1 : w0;
  uint16_t* dst = z ? d1 : d0;
  const int C = z ? 768 : 2304;
  const int R = 768;
  const int c0 = blockIdx.x * 32, r0 = blockIdx.y * 32;
#pragma unroll
  for (int i = 0; i < 32; i += 8)
    tile[ty + i][tx] = f16_bits(src[(size_t)(r0 + ty + i) * C + (c0 + tx)]);
  __syncthreads();
#pragma unroll
  for (int i = 0; i < 32; i += 8)
    dst[(size_t)(c0 + ty + i) * R + (r0 + tx)] = tile[tx][ty + i];
}

// ---------------- GEMM: C[m][n] = sum_k A[m][k] * Bt[n][k] + bias[n]
// 3-buffer counted-vmcnt pipeline + XCD-AWARE BLOCK SWIZZLE (T1): 1D grid,
// by = xcd*8 + (idx&7), bx = idx>>3 -> each XCD keeps 8 A-panels (1.5MB) +
// 1 B-panel (196KB) L2-resident; A and B fetched ~once per XCD instead of
// A x18 / B x64 re-reads under default round-robin placement.
// mode 0: store FP32 to o0 row-major [M][768]
// mode 1: QKV scatter: Q->o0, K->o1 as [B,H,N,64] f16 (Q pre-scaled);
//         V->o2 TRANSPOSED as [B,H,64,N] f16
__global__ __launch_bounds__(256) void gemm_bt(
    const _Float16* __restrict__ A, const _Float16* __restrict__ Bt,
    const float* __restrict__ bias, int K, int mode, int nbx,
    void* __restrict__ o0, _Float16* __restrict__ o1, _Float16* __restrict__ o2) {
  __shared__ __attribute__((aligned(16))) _Float16 As[3][128 * 32];
  __shared__ __attribute__((aligned(16))) _Float16 Bs[3][128 * 32];
  __shared__ float bias_s[128];
  const int tid = threadIdx.x;
  const int wv = tid >> 6;
  const int lane = tid & 63;
  const int quad = lane >> 4, l16 = lane & 15;
  const int wm = (wv >> 1) * 64, wn = (wv & 1) * 64;
  // XCD swizzle (bijective: gridDim.x = nbx*64, divisible by 8)
  const int bid = blockIdx.x;
  const int xcd = bid & 7, idx = bid >> 3;
  const int by = xcd * 8 + (idx & 7);
  const int bx = idx >> 3;
  const int m0 = by * 128, n0 = bx * 128;
  (void)nbx;

  if (tid < 128) bias_s[tid] = bias[n0 + tid];

  floatx4 acc[4][4];
#pragma unroll
  for (int i = 0; i < 4; ++i)
#pragma unroll
    for (int j = 0; j < 4; ++j) acc[i][j] = (floatx4){0.f, 0.f, 0.f, 0.f};

  // DMA mapping: wave wv stages A/B tile rows [wv*32, wv*32+32).
  const int gr = lane >> 2, gc = (lane & 3) * 8;
  const _Float16* Ag = A + (size_t)(m0 + wv * 32 + gr) * K + gc;
  const _Float16* Bg = Bt + (size_t)(n0 + wv * 32 + gr) * K + gc;
  const size_t K16 = (size_t)16 * K;

  auto STAGE = [&](int buf, int kt) {
    _Float16* As0 = &As[buf][wv * 1024];
    _Float16* Bs0 = &Bs[buf][wv * 1024];
    gload_lds16(Ag + kt, As0);
    gload_lds16(Ag + kt + K16, As0 + 512);
    gload_lds16(Bg + kt, Bs0);
    gload_lds16(Bg + kt + K16, Bs0 + 512);
  };
  auto COMPUTE = [&](int buf) {
    f16x8 af[4], bfr[4];
#pragma unroll
    for (int i = 0; i < 4; ++i)
      af[i] = *(const f16x8*)&As[buf][(wm + i * 16 + l16) * 32 + quad * 8];
#pragma unroll
    for (int j = 0; j < 4; ++j)
      bfr[j] = *(const f16x8*)&Bs[buf][(wn + j * 16 + l16) * 32 + quad * 8];
    __builtin_amdgcn_s_setprio(1);
#pragma unroll
    for (int i = 0; i < 4; ++i)
#pragma unroll
      for (int j = 0; j < 4; ++j)
        acc[i][j] = __builtin_amdgcn_mfma_f32_16x16x32_f16(af[i], bfr[j], acc[i][j], 0, 0, 0);
    __builtin_amdgcn_s_setprio(0);
  };

  STAGE(0, 0);
  STAGE(1, 32);
  const int nt = K >> 5;
  int b0 = 0, b1 = 1, b2 = 2;
#pragma unroll 1
  for (int t = 0; t < nt - 2; ++t) {
    // tile t landed (its 4 loads are the oldest; 4 newer stay in flight)
    asm volatile("s_waitcnt vmcnt(4)" ::: "memory");
    __builtin_amdgcn_s_barrier();
    STAGE(b2, (t + 2) * 32);
    COMPUTE(b0);
    const int tmp = b0; b0 = b1; b1 = b2; b2 = tmp;
  }
  asm volatile("s_waitcnt vmcnt(4)" ::: "memory");
  __builtin_amdgcn_s_barrier();
  COMPUTE(b0);
  b0 = b1;
  asm volatile("s_waitcnt vmcnt(0)" ::: "memory");
  __builtin_amdgcn_s_barrier();
  COMPUTE(b0);

  if (mode == 0) {
    float* of = (float*)o0;
#pragma unroll
    for (int i = 0; i < 4; ++i)
#pragma unroll
      for (int j = 0; j < 4; ++j) {
        const int col = n0 + wn + j * 16 + l16;
        const float b = bias_s[wn + j * 16 + l16];
        const int mrow = m0 + wm + i * 16 + quad * 4;
#pragma unroll
        for (int r = 0; r < 4; ++r)
          of[(size_t)(mrow + r) * DIMM + col] = acc[i][j][r] + b;
      }
  } else {
    const int sec = n0 / DIMM;  // 0=Q 1=K 2=V
    if (sec < 2) {
      _Float16* dst = (sec == 0) ? (_Float16*)o0 : o1;
      const float sc = (sec == 0) ? 0.18033688011112042f : 1.0f;  // 1/8 * log2(e)
#pragma unroll
      for (int i = 0; i < 4; ++i)
#pragma unroll
        for (int j = 0; j < 4; ++j) {
          const int n = n0 + wn + j * 16 + l16;
          const int c = n - sec * DIMM;
          const int h = c >> 6, d = c & 63;
          const float b = bias_s[wn + j * 16 + l16];
          const int mrow = m0 + wm + i * 16 + quad * 4;
#pragma unroll
          for (int r = 0; r < 4; ++r) {
            const int m = mrow + r;
            const int bb = m >> 12, nr = m & 4095;
            dst[(((size_t)(bb * NHEADS + h)) * NSEQ + nr) * HD + d] =
                (_Float16)((acc[i][j][r] + b) * sc);
          }
        }
    } else {
      // V^T: o2[((bb*NHEADS+h)*HD + d)*NSEQ + nr], nr consecutive over r
#pragma unroll
      for (int i = 0; i < 4; ++i)
#pragma unroll
        for (int j = 0; j < 4; ++j) {
          const int c = n0 + wn + j * 16 + l16 - 2 * DIMM;
          const int h = c >> 6, d = c & 63;
          const float b = bias_s[wn + j * 16 + l16];
          const int mrow = m0 + wm + i * 16 + quad * 4;
          const int bb = mrow >> 12, nr = mrow & 4095;  // same bb for r=0..3
          f16x4 v;
#pragma unroll
          for (int r = 0; r < 4; ++r) v[r] = (_Float16)(acc[i][j][r] + b);
          *(f16x4*)&o2[(((size_t)(bb * NHEADS + h)) * HD + d) * NSEQ + nr] = v;
        }
    }
  }
}

// ---------------- flash attention v8 (reverted from v9; measured best):
// P in-register via permlane, MFMA-ones row-sum, pipelined regions with
// per-region __syncthreads + same-region DMA issue. --------------------------
__global__ __launch_bounds__(256, 3) void attn(
    const _Float16* __restrict__ Qg, const _Float16* __restrict__ Kg,
    const _Float16* __restrict__ VTg, _Float16* __restrict__ ctx) {
  __shared__ __attribute__((aligned(16))) _Float16 Pt[128 * 64];  // Q stage
  __shared__ __attribute__((aligned(16))) _Float16 Ks[2][64 * 64];
  __shared__ __attribute__((aligned(16))) _Float16 VTs[2][64 * 64];
  const int tid = threadIdx.x;
  const int wv = tid >> 6, lane = tid & 63;
  const int quad = lane >> 4, l16 = lane & 15;
  // XCD swizzle: 768 blocks; id%8 = XCD -> each XCD owns 3 bh (K/V L2-resident)
  const int bi = blockIdx.x;
  const int xcd = bi & 7, j = bi >> 3;
  const int bh = xcd * 3 + (j >> 5);
  const int q0 = (j & 31) * 128;
  const int bb = bh / NHEADS, h = bh - bb * NHEADS;
  const _Float16* Qp = Qg + (size_t)bh * NSEQ * HD;
  const _Float16* Kp = Kg + (size_t)bh * NSEQ * HD;
  const _Float16* VTp = VTg + (size_t)bh * HD * NSEQ;

  const int krow = tid >> 3;
  // DMA lane->global-unit permute implements the XOR swizzle
  const int kcol = (((tid & 7) ^ ((tid >> 3) & 7)) * 8);

  // preamble: DMA Q tile [128][64] into Pt area + KV tile 0 into buf0
#pragma unroll
  for (int i = 0; i < 4; ++i)
    gload_lds16(Qp + (size_t)(q0 + i * 32 + krow) * HD + kcol, &Pt[(i * 256 + wv * 64) * 8]);
#pragma unroll
  for (int i = 0; i < 2; ++i) {
    gload_lds16(Kp + (size_t)(i * 32 + krow) * HD + kcol, &Ks[0][(i * 256 + wv * 64) * 8]);
    gload_lds16(VTp + (size_t)(i * 32 + krow) * NSEQ + kcol, &VTs[0][(i * 256 + wv * 64) * 8]);
  }
  __syncthreads();  // drains DMA: Q + buf0 visible

  f16x8 aq[2][2];
#pragma unroll
  for (int it = 0; it < 2; ++it)
#pragma unroll
    for (int ks = 0; ks < 2; ++ks)
      aq[it][ks] = *(const f16x8*)&Pt[swz(wv * 32 + it * 16 + l16, ks * 32 + quad * 8)];

  // issue DMA tile1 -> buf1 (drained at the first loop barrier)
#pragma unroll
  for (int i = 0; i < 2; ++i) {
    gload_lds16(Kp + (size_t)(64 + i * 32 + krow) * HD + kcol, &Ks[1][(i * 256 + wv * 64) * 8]);
    gload_lds16(VTp + (size_t)(i * 32 + krow) * NSEQ + 64 + kcol, &VTs[1][(i * 256 + wv * 64) * 8]);
  }

  f16x8 ones;
#pragma unroll
  for (int e = 0; e < 8; ++e) ones[e] = (_Float16)1.0f;

  floatx4 o[2][4];
  floatx4 lacc[2];
#pragma unroll
  for (int it = 0; it < 2; ++it) {
    lacc[it] = (floatx4){0.f, 0.f, 0.f, 0.f};
#pragma unroll
    for (int jn = 0; jn < 4; ++jn) o[it][jn] = (floatx4){0.f, 0.f, 0.f, 0.f};
  }

  f16x8 vr[2][4];   // V(t) fragments carried across the barrier
  f16x8 ap[2][2];   // P(t) A-fragments, built in-register by SMAX

  // S^T = K . Q^T  (exp2-domain: Q pre-scaled by 0.125*log2e)
  auto QKT = [&](const _Float16* bK, floatx4 (&s)[2][4]) {
#pragma unroll
    for (int ks = 0; ks < 2; ++ks) {
#pragma unroll
      for (int im = 0; im < 4; ++im) {
        const f16x8 bk = *(const f16x8*)&bK[swz(im * 16 + l16, ks * 32 + quad * 8)];
        s[0][im] = __builtin_amdgcn_mfma_f32_16x16x32_f16(bk, aq[0][ks], s[0][im], 0, 0, 0);
        s[1][im] = __builtin_amdgcn_mfma_f32_16x16x32_f16(bk, aq[1][ks], s[1][im], 0, 0, 0);
      }
    }
  };
  auto LDVR = [&](const _Float16* bV) {
#pragma unroll
    for (int kk = 0; kk < 2; ++kk)
#pragma unroll
      for (int jn = 0; jn < 4; ++jn)
        vr[kk][jn] = *(const f16x8*)&bV[swz(jn * 16 + l16, kk * 32 + quad * 8)];
  };
  // p = exp2(s); pkrtz pack; permlane quad-redistribute C->A layout in-reg.
  // (row-sum l is NOT accumulated here; PV's MFMA-ones handles it.)
  auto SMAX = [&](floatx4 (&s)[2][4]) {
#pragma unroll
    for (int it = 0; it < 2; ++it) {
      uint32_t w[4][2];
#pragma unroll
      for (int im = 0; im < 4; ++im) {
        float p0 = __builtin_amdgcn_exp2f(s[it][im][0]);
        float p1 = __builtin_amdgcn_exp2f(s[it][im][1]);
        float p2 = __builtin_amdgcn_exp2f(s[it][im][2]);
        float p3 = __builtin_amdgcn_exp2f(s[it][im][3]);
        w[im][0] = pkrtz(p0, p1);
        w[im][1] = pkrtz(p2, p3);
      }
#pragma unroll
      for (int kk = 0; kk < 2; ++kk) {
        uint32_t a = w[2 * kk][0], c = w[2 * kk + 1][0];
        uint32_t b = w[2 * kk][1], d = w[2 * kk + 1][1];
        asm("v_permlane32_swap_b32 %0, %1" : "+v"(a), "+v"(c));
        asm("v_permlane16_swap_b32 %0, %1" : "+v"(a), "+v"(c));
        asm("v_permlane32_swap_b32 %0, %1" : "+v"(b), "+v"(d));
        asm("v_permlane16_swap_b32 %0, %1" : "+v"(b), "+v"(d));
        const u32x4 pk = {a, b, c, d};
        ap[kk][it] = __builtin_bit_cast(f16x8, pk);
      }
    }
  };
  auto PV = [&]() {
#pragma unroll
    for (int kk = 0; kk < 2; ++kk) {
      lacc[0] = __builtin_amdgcn_mfma_f32_16x16x32_f16(ap[kk][0], ones, lacc[0], 0, 0, 0);
      lacc[1] = __builtin_amdgcn_mfma_f32_16x16x32_f16(ap[kk][1], ones, lacc[1], 0, 0, 0);
#pragma unroll
      for (int jn = 0; jn < 4; ++jn) {
        o[0][jn] = __builtin_amdgcn_mfma_f32_16x16x32_f16(ap[kk][0], vr[kk][jn], o[0][jn], 0, 0, 0);
        o[1][jn] = __builtin_amdgcn_mfma_f32_16x16x32_f16(ap[kk][1], vr[kk][jn], o[1][jn], 0, 0, 0);
      }
    }
  };

  // region 0 (no PV): QK^T(0), stash V(0) in regs, softmax(0) -> ap
  {
    floatx4 s[2][4];
#pragma unroll
    for (int it = 0; it < 2; ++it)
#pragma unroll
      for (int im = 0; im < 4; ++im) s[it][im] = (floatx4){0.f, 0.f, 0.f, 0.f};
    __builtin_amdgcn_s_setprio(1);
    QKT(Ks[0], s);
    __builtin_amdgcn_s_setprio(0);
    LDVR(VTs[0]);
    SMAX(s);
  }

  // region t (t>=1): barrier; DMA(t+1); QK^T(t) + PV(t-1) MFMA cluster;
  // reload vr = V(t); softmax(t) -> ap (in-register) tail.
  auto REGION = [&](const _Float16* bK, const _Float16* bV,
                    _Float16* wK, _Float16* wV, int kvn, bool dodma) {
    __syncthreads();  // readers of wK/wV done; DMA(t) drained (vmcnt0)
    if (dodma) {
#pragma unroll
      for (int i = 0; i < 2; ++i) {
        gload_lds16(Kp + (size_t)(kvn + i * 32 + krow) * HD + kcol, &wK[(i * 256 + wv * 64) * 8]);
        gload_lds16(VTp + (size_t)(i * 32 + krow) * NSEQ + kvn + kcol, &wV[(i * 256 + wv * 64) * 8]);
      }
    }
    floatx4 s[2][4];
#pragma unroll
    for (int it = 0; it < 2; ++it)
#pragma unroll
      for (int im = 0; im < 4; ++im) s[it][im] = (floatx4){0.f, 0.f, 0.f, 0.f};
    __builtin_amdgcn_s_setprio(1);
    QKT(bK, s);
    PV();      // consumes ap,vr = region t-1; accumulates o and lacc
    __builtin_amdgcn_s_setprio(0);
    LDVR(bV);  // vr = V(t) for next region's PV
    SMAX(s);   // ap = P(t) in-register
  };

#pragma unroll 1
  for (int p = 0; p < 31; ++p) {
    const int t0 = 2 * p + 1;
    REGION(Ks[1], VTs[1], Ks[0], VTs[0], (t0 + 1) * 64, true);
    REGION(Ks[0], VTs[0], Ks[1], VTs[1], (t0 + 2) * 64, true);
  }
  REGION(Ks[1], VTs[1], Ks[0], VTs[0], 0, false);  // t=63, no DMA
  PV();  // final PV(63): all in-register

  // epilogue: l[q] sits in lacc[it][r] on exactly this lane -- no shuffles
#pragma unroll
  for (int it = 0; it < 2; ++it)
#pragma unroll
    for (int r = 0; r < 4; ++r) {
      const int q = q0 + wv * 32 + it * 16 + quad * 4 + r;
      const float inv = 1.0f / lacc[it][r];
      _Float16* dst = ctx + (size_t)(bb * NSEQ + q) * DIMM + h * HD;
#pragma unroll
      for (int jn = 0; jn < 4; ++jn)
        dst[jn * 16 + l16] = (_Float16)(o[it][jn][r] * inv);
    }
}

extern "C" void kernel_launch(void* const* d_in, const int* in_sizes, int n_in,
                              void* d_out, int out_size, void* d_ws, size_t ws_size,
                              hipStream_t stream) {
  char* ws = (char*)d_ws;
  _Float16* xc = (_Float16*)ws;      ws += (size_t)8192 * 768 * 2;
  _Float16* wqkvT = (_Float16*)ws;   ws += (size_t)2304 * 768 * 2;
  _Float16* wprojT = (_Float16*)ws;  ws += (size_t)768 * 768 * 2;
  const size_t qkv_elems = (size_t)2 * NHEADS * NSEQ * HD;
  _Float16* Qb = (_Float16*)ws;      ws += qkv_elems * 2;
  _Float16* Kb = (_Float16*)ws;      ws += qkv_elems * 2;
  _Float16* VTb = (_Float16*)ws;     ws += qkv_elems * 2;
  _Float16* ctx = xc;  // x dead after QKV GEMM; reuse as attention output

  const dim3 tb(32, 8, 1);
  const dim3 b256(256, 1, 1);
  hipLaunchKernelGGL(prologue, dim3(72, 24, 3), tb, 0, stream,
                     (const float*)d_in[1], (const float*)d_in[3],
                     (uint16_t*)wqkvT, (uint16_t*)wprojT,
                     (const float4*)d_in[0], (f16x8*)xc, 8192 * 768 / 8);
  hipLaunchKernelGGL(gemm_bt, dim3(18 * 64, 1, 1), b256, 0, stream,
                     xc, wqkvT, (const float*)d_in[2], 768, 1, 18,
                     (void*)Qb, Kb, VTb);
  hipLaunchKernelGGL(attn, dim3(768, 1, 1), b256, 0, stream, Qb, Kb, VTb, ctx);
  hipLaunchKernelGGL(gemm_bt, dim3(6 * 64, 1, 1), b256, 0, stream,
                     ctx, wprojT, (const float*)d_in[4], 768, 0, 6, d_out,
                     (_Float16*)nullptr, (_Float16*)nullptr);
}